// Round 4
// baseline (1581.561 us; speedup 1.0000x reference)
//
#include <hip/hip_runtime.h>
#include <math.h>

typedef __bf16 bf16;
typedef __attribute__((ext_vector_type(8))) __bf16 bf16x8;
typedef __attribute__((ext_vector_type(4))) float f32x4;

#define LDSP(p) ((__attribute__((address_space(3))) void*)(p))
#define GLBP(p) ((const __attribute__((address_space(1))) void*)(p))

static constexpr int NTOK = 8192;   // B*T
static constexpr int CD   = 1024;   // C
static constexpr int HD   = 128;    // head dim
static constexpr int TS   = 2048;   // T
static constexpr int NB   = 4;      // B

__device__ __forceinline__ void split2(float x, bf16& h, bf16& l) {
  bf16 hh = (bf16)x;
  h = hh;
  l = (bf16)(x - (float)hh);
}

__device__ __forceinline__ float blk_sum(float v, float* sm) {
  #pragma unroll
  for (int o = 32; o > 0; o >>= 1) v += __shfl_down(v, o);
  if ((threadIdx.x & 63) == 0) sm[threadIdx.x >> 6] = v;
  __syncthreads();
  v = sm[0] + sm[1] + sm[2] + sm[3];
  __syncthreads();
  return v;
}

__device__ __forceinline__ float blk_max(float v, float* sm) {
  #pragma unroll
  for (int o = 32; o > 0; o >>= 1) v = fmaxf(v, __shfl_down(v, o));
  if ((threadIdx.x & 63) == 0) sm[threadIdx.x >> 6] = v;
  __syncthreads();
  v = fmaxf(fmaxf(sm[0], sm[1]), fmaxf(sm[2], sm[3]));
  __syncthreads();
  return v;
}

// ---------------- LayerNorm: bf16 hi/lo split out ---------------------------
__global__ __launch_bounds__(256) void ln_kernel(
    const float* __restrict__ x, const float* __restrict__ w, const float* __restrict__ b,
    bf16* __restrict__ outh, bf16* __restrict__ outl)
{
  __shared__ float sm[4];
  size_t ro = (size_t)blockIdx.x * CD;
  float4 v = ((const float4*)(x + ro))[threadIdx.x];
  float s = v.x + v.y + v.z + v.w;
  s = blk_sum(s, sm);
  float mean = s * (1.f / CD);
  float dx = v.x - mean, dy = v.y - mean, dz = v.z - mean, dw = v.w - mean;
  float sq = dx*dx + dy*dy + dz*dz + dw*dw;
  sq = blk_sum(sq, sm);
  float rstd = rsqrtf(sq * (1.f / CD) + 1e-5f);
  float4 wv = ((const float4*)w)[threadIdx.x];
  float4 bv = ((const float4*)b)[threadIdx.x];
  float y0 = dx*rstd*wv.x + bv.x, y1 = dy*rstd*wv.y + bv.y;
  float y2 = dz*rstd*wv.z + bv.z, y3 = dw*rstd*wv.w + bv.w;
  size_t c0 = ro + (size_t)threadIdx.x * 4;
  split2(y0, outh[c0+0], outl[c0+0]);
  split2(y1, outh[c0+1], outl[c0+1]);
  split2(y2, outh[c0+2], outl[c0+2]);
  split2(y3, outh[c0+3], outl[c0+3]);
}

// ---------------- Gating: one wave per token (reads split n) ----------------
__global__ __launch_bounds__(256) void gating_kernel(
    const bf16* __restrict__ nh, const bf16* __restrict__ nl,
    const float* __restrict__ sim, const float* __restrict__ gates,
    float* __restrict__ rw)
{
  int t = blockIdx.x * 4 + (threadIdx.x >> 6);
  int lane = threadIdx.x & 63;
  const bf16* xh = nh + (size_t)t * CD;
  const bf16* xl = nl + (size_t)t * CD;
  float acc[8] = {0,0,0,0,0,0,0,0};
  float sn2[8] = {0,0,0,0,0,0,0,0};
  float nn = 0.f;
  for (int c = lane; c < CD; c += 64) {
    float xv = (float)xh[c] + (float)xl[c];
    nn += xv * xv;
    float4 s0 = ((const float4*)sim)[c*2];
    float4 s1 = ((const float4*)sim)[c*2+1];
    float sv[8] = {s0.x,s0.y,s0.z,s0.w,s1.x,s1.y,s1.z,s1.w};
    #pragma unroll
    for (int e = 0; e < 8; ++e) { acc[e] += xv * sv[e]; sn2[e] += sv[e]*sv[e]; }
  }
  #pragma unroll
  for (int o = 32; o > 0; o >>= 1) {
    nn += __shfl_down(nn, o);
    #pragma unroll
    for (int e = 0; e < 8; ++e) {
      acc[e] += __shfl_down(acc[e], o);
      sn2[e] += __shfl_down(sn2[e], o);
    }
  }
  if (lane == 0) {
    float invn = 1.f / fmaxf(sqrtf(nn), 1e-12f);
    float logits[8], gated[8], mask[8];
    int act = 0;
    #pragma unroll
    for (int e = 0; e < 8; ++e) {
      float invs = 1.f / fmaxf(sqrtf(sn2[e]), 1e-12f);
      float sg = 1.f / (1.f + expf(-gates[e]));
      float lg = acc[e] * invn * invs - sg;
      logits[e] = lg;
      gated[e] = fmaxf(lg, 0.f);
      mask[e] = (gated[e] > 0.f) ? 1.f : 0.f;
      act += (gated[e] > 0.f) ? 1 : 0;
    }
    if (act == 0) {  // forced top-2 (first-index tie semantics like lax.top_k)
      int i1 = 0;
      #pragma unroll
      for (int e = 1; e < 8; ++e) if (logits[e] > logits[i1]) i1 = e;
      int i2 = (i1 == 0) ? 1 : 0;
      #pragma unroll
      for (int e = 0; e < 8; ++e) if (e != i1 && e != i2 && logits[e] > logits[i2]) i2 = e;
      mask[i1] = 1.f; mask[i2] = 1.f;
    }
    float mx = -3.4e38f;
    #pragma unroll
    for (int e = 0; e < 8; ++e) if (mask[e] > 0.f) mx = fmaxf(mx, gated[e]);
    float ssum = 0.f, p[8];
    #pragma unroll
    for (int e = 0; e < 8; ++e) { p[e] = (mask[e] > 0.f) ? expf(gated[e] - mx) : 0.f; ssum += p[e]; }
    float inv = 1.f / ssum;
    #pragma unroll
    for (int e = 0; e < 8; ++e) rw[(size_t)t*8 + e] = p[e] * inv;
  }
}

// ------------- transpose + (optional) bf16 split: out[j][i] = src[i][j] -----
__global__ __launch_bounds__(256) void transpose_split(
    const float* __restrict__ src, bf16* __restrict__ dsth, bf16* __restrict__ dstl,
    int ldsrc, int lddst, long sBatch, long dBatch)
{
  __shared__ float tile[32][33];
  src  += (size_t)blockIdx.z * sBatch;
  dsth += (size_t)blockIdx.z * dBatch;
  if (dstl) dstl += (size_t)blockIdx.z * dBatch;
  int j0 = blockIdx.x * 32;   // src col
  int i0 = blockIdx.y * 32;   // src row
  int tx = threadIdx.x & 31, ty = threadIdx.x >> 5;
  #pragma unroll
  for (int r = 0; r < 32; r += 8)
    tile[ty + r][tx] = src[(size_t)(i0 + ty + r) * ldsrc + j0 + tx];
  __syncthreads();
  #pragma unroll
  for (int r = 0; r < 32; r += 8) {
    float v = tile[tx][ty + r];
    size_t o = (size_t)(j0 + ty + r) * lddst + i0 + tx;
    bf16 hh, ll; split2(v, hh, ll);
    dsth[o] = hh;
    if (dstl) dstl[o] = ll;
  }
}

// ---------------- GEMM: C(MxN) = A(MxK) * B^T(NxK), bf16 mfma ---------------
// SPLIT: hi/lo bf16 pair inputs (3 mfma/product).
// EPI: 0 f32 store | 1 f32 +res | 2 gelu*rw -> bf16 | 3 split-bf16 (v*scale)
// CAUSAL: skip tiles with n0 > m0.
template<int SPLIT, int EPI, int CAUSAL>
__global__ __launch_bounds__(256) void gemm_kernel(
    const bf16* __restrict__ Ah, const bf16* __restrict__ Al,
    const bf16* __restrict__ Bh, const bf16* __restrict__ Bl,
    float* __restrict__ Co, const float* __restrict__ res,
    const float* __restrict__ rwp, bf16* __restrict__ outb,
    bf16* __restrict__ outb2, float scale,
    int M, int N, int K, long aB, long bB, long cB)
{
  int n0 = blockIdx.x * 128, m0 = blockIdx.y * 128;
  if (CAUSAL && n0 > m0) return;
  const bf16* aH = Ah + (size_t)blockIdx.z * aB + (size_t)m0 * K;
  const bf16* bH = Bh + (size_t)blockIdx.z * bB + (size_t)n0 * K;
  const bf16* aL = nullptr; const bf16* bL = nullptr;
  if constexpr (SPLIT) {
    aL = Al + (size_t)blockIdx.z * aB + (size_t)m0 * K;
    bL = Bl + (size_t)blockIdx.z * bB + (size_t)n0 * K;
  }
  __shared__ bf16 As[SPLIT + 1][128 * 32];
  __shared__ bf16 Bs[SPLIT + 1][128 * 32];
  const f32x4 fz = {0.f, 0.f, 0.f, 0.f};
  f32x4 acc[4][4];
  #pragma unroll
  for (int i = 0; i < 4; ++i)
    #pragma unroll
    for (int j = 0; j < 4; ++j) acc[i][j] = fz;

  int lane = threadIdx.x & 63;
  int wv = threadIdx.x >> 6;
  int wr = wv >> 1, wc = wv & 1;
  int l15 = lane & 15;
  int kOff = (lane >> 4) * 8;
  int t = threadIdx.x;

  for (int k0 = 0; k0 < K; k0 += 32) {
    #pragma unroll
    for (int cch = 0; cch < 2; ++cch) {
      int ci = t + cch * 256;
      int row = ci >> 2;
      int kc = (ci & 3) * 8;
      size_t go = (size_t)row * K + (size_t)(k0 + kc);
      __builtin_amdgcn_global_load_lds(GLBP(aH + go), LDSP(&As[0][ci * 8]), 16, 0, 0);
      __builtin_amdgcn_global_load_lds(GLBP(bH + go), LDSP(&Bs[0][ci * 8]), 16, 0, 0);
      if constexpr (SPLIT) {
        __builtin_amdgcn_global_load_lds(GLBP(aL + go), LDSP(&As[1][ci * 8]), 16, 0, 0);
        __builtin_amdgcn_global_load_lds(GLBP(bL + go), LDSP(&Bs[1][ci * 8]), 16, 0, 0);
      }
    }
    __syncthreads();
    bf16x8 aF[2][4], bF[2][4];
    #pragma unroll
    for (int i = 0; i < 4; ++i) {
      aF[0][i] = *(const bf16x8*)&As[0][(wr*64 + i*16 + l15) * 32 + kOff];
      bF[0][i] = *(const bf16x8*)&Bs[0][(wc*64 + i*16 + l15) * 32 + kOff];
      if constexpr (SPLIT) {
        aF[1][i] = *(const bf16x8*)&As[1][(wr*64 + i*16 + l15) * 32 + kOff];
        bF[1][i] = *(const bf16x8*)&Bs[1][(wc*64 + i*16 + l15) * 32 + kOff];
      }
    }
    #pragma unroll
    for (int i = 0; i < 4; ++i)
      #pragma unroll
      for (int j = 0; j < 4; ++j) {
        acc[i][j] = __builtin_amdgcn_mfma_f32_16x16x32_bf16(aF[0][i], bF[0][j], acc[i][j], 0, 0, 0);
        if constexpr (SPLIT) {
          acc[i][j] = __builtin_amdgcn_mfma_f32_16x16x32_bf16(aF[0][i], bF[1][j], acc[i][j], 0, 0, 0);
          acc[i][j] = __builtin_amdgcn_mfma_f32_16x16x32_bf16(aF[1][i], bF[0][j], acc[i][j], 0, 0, 0);
        }
      }
    __syncthreads();
  }

  size_t cz = (size_t)blockIdx.z * cB;
  #pragma unroll
  for (int i = 0; i < 4; ++i) {
    #pragma unroll
    for (int j = 0; j < 4; ++j) {
      int r0 = m0 + wr*64 + i*16 + (lane >> 4) * 4;
      int ccol = n0 + wc*64 + j*16 + l15;
      #pragma unroll
      for (int jj = 0; jj < 4; ++jj) {
        float v = acc[i][j][jj];
        size_t idx = cz + (size_t)(r0 + jj) * N + ccol;
        if constexpr (EPI == 0) {
          Co[idx] = v;
        } else if constexpr (EPI == 1) {
          Co[idx] = v + res[idx];
        } else if constexpr (EPI == 2) {
          float gl = 0.5f * v * (1.f + erff(v * 0.70710678118654752f));
          float wgt = rwp[(size_t)(r0 + jj) * 8 + (ccol >> 10)];
          outb[idx] = (bf16)(gl * wgt);
        } else {
          split2(v * scale, outb[idx], outb2[idx]);
        }
      }
    }
  }
}

// ---------------- per-token expert reduce of QKV ----------------------------
__global__ __launch_bounds__(128) void qkv_reduce_kernel(
    const float* __restrict__ qkv, const float* __restrict__ rw,
    bf16* __restrict__ qh, bf16* __restrict__ ql,
    bf16* __restrict__ kh, bf16* __restrict__ kl,
    float* __restrict__ vf)
{
  int t = blockIdx.x, sel = blockIdx.y, h = threadIdx.x;
  const float* src = qkv + (size_t)t * 3072 + sel * 1024 + h;
  const float* rp = rw + (size_t)t * 8;
  float acc = 0.f;
  #pragma unroll
  for (int e = 0; e < 8; ++e) acc += rp[e] * src[e * 128];
  size_t o = (size_t)t * HD + h;
  if (sel == 0)      split2(acc, qh[o], ql[o]);
  else if (sel == 1) split2(acc, kh[o], kl[o]);
  else               vf[o] = acc;
}

// ------- causal softmax, IN-PLACE over split-bf16 scores -> split-bf16 P ----
__global__ __launch_bounds__(256) void softmax_kernel(
    bf16* __restrict__ ph, bf16* __restrict__ pl)
{
  __shared__ float sm[4];
  int t = blockIdx.x;
  size_t ro = ((size_t)blockIdx.y * TS + t) * TS;
  float vals[8];
  float mx = -3.4e38f;
  #pragma unroll
  for (int u = 0; u < 8; ++u) {
    int j = threadIdx.x + u * 256;
    float v = (j <= t) ? ((float)ph[ro + j] + (float)pl[ro + j]) : -3.4e38f;
    vals[u] = v;
    mx = fmaxf(mx, v);
  }
  mx = blk_max(mx, sm);
  float sum = 0.f;
  #pragma unroll
  for (int u = 0; u < 8; ++u) {
    int j = threadIdx.x + u * 256;
    float e = (j <= t) ? expf(vals[u] - mx) : 0.f;
    vals[u] = e;
    sum += e;
  }
  sum = blk_sum(sum, sm);
  float inv = 1.f / sum;
  #pragma unroll
  for (int u = 0; u < 8; ++u) {
    int j = threadIdx.x + u * 256;
    split2(vals[u] * inv, ph[ro + j], pl[ro + j]);
  }
}

// ------------- expand: A'[t][e*128+h] = rw[t][e]*attn[t][h] (split) ---------
__global__ __launch_bounds__(256) void expand_kernel(
    const float* __restrict__ attn, const float* __restrict__ rw,
    bf16* __restrict__ ah, bf16* __restrict__ al)
{
  size_t i = (size_t)blockIdx.x * 256 + threadIdx.x;
  int t = (int)(i >> 10), col = (int)(i & 1023);
  int e = col >> 7, h = col & 127;
  float v = rw[(size_t)t*8 + e] * attn[(size_t)t*HD + h];
  split2(v, ah[i], al[i]);
}

// ============================================================================
extern "C" void kernel_launch(void* const* d_in, const int* in_sizes, int n_in,
                              void* d_out, int out_size, void* d_ws, size_t ws_size,
                              hipStream_t stream) {
  const float* x        = (const float*)d_in[0];
  const float* ln1w     = (const float*)d_in[1];
  const float* ln1b     = (const float*)d_in[2];
  const float* ln2w     = (const float*)d_in[3];
  const float* ln2b     = (const float*)d_in[4];
  const float* smha_sim = (const float*)d_in[5];
  const float* smha_g   = (const float*)d_in[6];
  const float* q_proj   = (const float*)d_in[7];
  const float* k_proj   = (const float*)d_in[8];
  const float* v_proj   = (const float*)d_in[9];
  const float* o_proj   = (const float*)d_in[10];
  const float* moe_sim  = (const float*)d_in[11];
  const float* moe_g    = (const float*)d_in[12];
  const float* w1       = (const float*)d_in[13];
  const float* w2       = (const float*)d_in[14];
  float* out = (float*)d_out;
  (void)in_sizes; (void)n_in; (void)out_size;

  // ---- workspace layout (227 MB peak, phase-aliased arenas) ----
  char* ws = (char*)d_ws;
  size_t off = 0;
  auto alloc = [&](size_t bytes) -> char* {
    char* p = ws + off;
    off += (bytes + 255) & ~(size_t)255;
    return p;
  };
  float* hs    = (float*)alloc(33554432);   // (8192,1024) f32      [live: O-proj -> end]
  bf16*  n1h   = (bf16*) alloc(16777216);   // split LN out         [LN1->QKV, LN2->MoE]
  bf16*  n1l   = (bf16*) alloc(16777216);
  float* rwA   = (float*)alloc(262144);
  float* rwM   = (float*)alloc(262144);
  bf16*  OtH   = (bf16*) alloc(2097152);
  bf16*  OtL   = (bf16*) alloc(2097152);
  bf16*  qh    = (bf16*) alloc(2097152);
  bf16*  ql    = (bf16*) alloc(2097152);
  bf16*  kh    = (bf16*) alloc(2097152);
  bf16*  kl    = (bf16*) alloc(2097152);
  float* vf    = (float*)alloc(4194304);
  bf16*  vth   = (bf16*) alloc(2097152);
  bf16*  vtl   = (bf16*) alloc(2097152);
  float* attnH = (float*)alloc(4194304);
  char*  segW  = alloc(33554432);           // Wqkv split | W1t+W2t
  char*  segB  = alloc(100663296);          // qkvAll | scores/P split | Ae split | interQ
  size_t NEED = off;
  if (ws_size < NEED) return;  // constant per-call; yields clean numeric-fail diagnostic

  bf16* WqkvH = (bf16*)segW;                      // 3072x1024
  bf16* WqkvL = (bf16*)(segW + 6291456);
  bf16* W1t   = (bf16*)segW;                      // 8192x1024
  bf16* W2t   = (bf16*)(segW + 16777216);         // 1024x8192
  float* qkvAll = (float*)segB;                   // 8192x3072 f32
  bf16* Ph    = (bf16*)segB;                      // 4x2048x2048 (scores then P, in-place)
  bf16* Pl    = (bf16*)(segB + 33554432);
  bf16* Aeh   = (bf16*)segB;                      // 8192x1024
  bf16* Ael   = (bf16*)(segB + 16777216);
  bf16* interQ= (bf16*)segB;                      // 2048x8192 (per M-quarter)

  // ---- attention weights: transpose + split ----
  transpose_split<<<dim3(4, 32, 8), 256, 0, stream>>>(q_proj, WqkvH, WqkvL, 128, 1024, 131072L, 131072L);
  transpose_split<<<dim3(4, 32, 8), 256, 0, stream>>>(k_proj, WqkvH + 1048576, WqkvL + 1048576, 128, 1024, 131072L, 131072L);
  transpose_split<<<dim3(4, 32, 8), 256, 0, stream>>>(v_proj, WqkvH + 2097152, WqkvL + 2097152, 128, 1024, 131072L, 131072L);
  transpose_split<<<dim3(32, 4, 8), 256, 0, stream>>>(o_proj, OtH, OtL, 1024, 1024, 131072L, 128L);

  // ---- LN1 + attention gating ----
  ln_kernel<<<NTOK, 256, 0, stream>>>(x, ln1w, ln1b, n1h, n1l);
  gating_kernel<<<NTOK / 4, 256, 0, stream>>>(n1h, n1l, smha_sim, smha_g, rwA);

  // ---- QKV all-expert GEMM (split) + rw reduce ----
  gemm_kernel<1, 0, 0><<<dim3(24, 64, 1), 256, 0, stream>>>(
      n1h, n1l, WqkvH, WqkvL, qkvAll, nullptr, nullptr, nullptr, nullptr, 1.f,
      NTOK, 3072, CD, 0L, 0L, 0L);
  qkv_reduce_kernel<<<dim3(NTOK, 3), 128, 0, stream>>>(qkvAll, rwA, qh, ql, kh, kl, vf);
  transpose_split<<<dim3(4, 64, 4), 256, 0, stream>>>(vf, vth, vtl, 128, 2048, 262144L, 262144L);

  // ---- attention: scores (split-bf16, scale folded), softmax in-place, PV --
  gemm_kernel<1, 3, 1><<<dim3(16, 16, 4), 256, 0, stream>>>(
      qh, ql, kh, kl, nullptr, nullptr, nullptr, Ph, Pl, 0.08838834764831845f,
      TS, TS, HD, (long)TS * HD, (long)TS * HD, (long)TS * TS);
  softmax_kernel<<<dim3(TS, NB), 256, 0, stream>>>(Ph, Pl);
  gemm_kernel<1, 0, 0><<<dim3(1, 16, 4), 256, 0, stream>>>(
      Ph, Pl, vth, vtl, attnH, nullptr, nullptr, nullptr, nullptr, 1.f,
      TS, HD, TS, (long)TS * TS, (long)HD * TS, (long)TS * HD);

  // ---- O-projection with rw folded into A, +x residual -> hs ----
  expand_kernel<<<NTOK * CD / 256, 256, 0, stream>>>(attnH, rwA, Aeh, Ael);
  gemm_kernel<1, 1, 0><<<dim3(8, 64, 1), 256, 0, stream>>>(
      Aeh, Ael, OtH, OtL, hs, x, nullptr, nullptr, nullptr, 1.f,
      NTOK, CD, CD, 0L, 0L, 0L);

  // ---- LN2 + MoE gating ----
  ln_kernel<<<NTOK, 256, 0, stream>>>(hs, ln2w, ln2b, n1h, n1l);  // n2 split
  gating_kernel<<<NTOK / 4, 256, 0, stream>>>(n1h, n1l, moe_sim, moe_g, rwM);

  // ---- MoE weights (plain bf16) ----
  transpose_split<<<dim3(32, 32, 8), 256, 0, stream>>>(w1, W1t, nullptr, 1024, 1024, 1048576L, 1048576L);
  transpose_split<<<dim3(32, 32, 8), 256, 0, stream>>>(w2, W2t, nullptr, 1024, 8192, 1048576L, 1024L);

  // ---- MoE in 4 M-quarters through one 33.5MB inter buffer ----
  for (int q = 0; q < 4; ++q) {
    gemm_kernel<0, 2, 0><<<dim3(64, 16, 1), 256, 0, stream>>>(
        n1h + (size_t)q * 2097152, nullptr, W1t, nullptr,
        nullptr, nullptr, rwM + (size_t)q * 16384, interQ, nullptr, 1.f,
        2048, 8192, CD, 0L, 0L, 0L);
    gemm_kernel<0, 1, 0><<<dim3(8, 16, 1), 256, 0, stream>>>(
        interQ, nullptr, W2t, nullptr,
        out + (size_t)q * 2097152, hs + (size_t)q * 2097152, nullptr, nullptr, nullptr, 1.f,
        2048, CD, 8192, 0L, 0L, 0L);
  }
}

// Round 5
// 1100.593 us; speedup vs baseline: 1.4370x; 1.4370x over previous
//
#include <hip/hip_runtime.h>
#include <math.h>

typedef __bf16 bf16;
typedef __attribute__((ext_vector_type(8))) __bf16 bf16x8;
typedef __attribute__((ext_vector_type(4))) float f32x4;

#define LDSP(p) ((__attribute__((address_space(3))) void*)(p))
#define GLBP(p) ((const __attribute__((address_space(1))) void*)(p))

static constexpr int NTOK = 8192;   // B*T
static constexpr int CD   = 1024;   // C
static constexpr int HD   = 128;    // head dim
static constexpr int TS   = 2048;   // T
static constexpr int NB   = 4;      // B

__device__ __forceinline__ void split2(float x, bf16& h, bf16& l) {
  bf16 hh = (bf16)x;
  h = hh;
  l = (bf16)(x - (float)hh);
}

__device__ __forceinline__ float blk_sum(float v, float* sm) {
  #pragma unroll
  for (int o = 32; o > 0; o >>= 1) v += __shfl_down(v, o);
  if ((threadIdx.x & 63) == 0) sm[threadIdx.x >> 6] = v;
  __syncthreads();
  v = sm[0] + sm[1] + sm[2] + sm[3];
  __syncthreads();
  return v;
}

__device__ __forceinline__ float blk_max(float v, float* sm) {
  #pragma unroll
  for (int o = 32; o > 0; o >>= 1) v = fmaxf(v, __shfl_down(v, o));
  if ((threadIdx.x & 63) == 0) sm[threadIdx.x >> 6] = v;
  __syncthreads();
  v = fmaxf(fmaxf(sm[0], sm[1]), fmaxf(sm[2], sm[3]));
  __syncthreads();
  return v;
}

// ---------------- LayerNorm: bf16 hi/lo split out ---------------------------
__global__ __launch_bounds__(256) void ln_kernel(
    const float* __restrict__ x, const float* __restrict__ w, const float* __restrict__ b,
    bf16* __restrict__ outh, bf16* __restrict__ outl)
{
  __shared__ float sm[4];
  size_t ro = (size_t)blockIdx.x * CD;
  float4 v = ((const float4*)(x + ro))[threadIdx.x];
  float s = v.x + v.y + v.z + v.w;
  s = blk_sum(s, sm);
  float mean = s * (1.f / CD);
  float dx = v.x - mean, dy = v.y - mean, dz = v.z - mean, dw = v.w - mean;
  float sq = dx*dx + dy*dy + dz*dz + dw*dw;
  sq = blk_sum(sq, sm);
  float rstd = rsqrtf(sq * (1.f / CD) + 1e-5f);
  float4 wv = ((const float4*)w)[threadIdx.x];
  float4 bv = ((const float4*)b)[threadIdx.x];
  float y0 = dx*rstd*wv.x + bv.x, y1 = dy*rstd*wv.y + bv.y;
  float y2 = dz*rstd*wv.z + bv.z, y3 = dw*rstd*wv.w + bv.w;
  size_t c0 = ro + (size_t)threadIdx.x * 4;
  split2(y0, outh[c0+0], outl[c0+0]);
  split2(y1, outh[c0+1], outl[c0+1]);
  split2(y2, outh[c0+2], outl[c0+2]);
  split2(y3, outh[c0+3], outl[c0+3]);
}

// ---------------- Gating: one wave per token (reads split n) ----------------
__global__ __launch_bounds__(256) void gating_kernel(
    const bf16* __restrict__ nh, const bf16* __restrict__ nl,
    const float* __restrict__ sim, const float* __restrict__ gates,
    float* __restrict__ rw)
{
  int t = blockIdx.x * 4 + (threadIdx.x >> 6);
  int lane = threadIdx.x & 63;
  const bf16* xh = nh + (size_t)t * CD;
  const bf16* xl = nl + (size_t)t * CD;
  float acc[8] = {0,0,0,0,0,0,0,0};
  float sn2[8] = {0,0,0,0,0,0,0,0};
  float nn = 0.f;
  for (int c = lane; c < CD; c += 64) {
    float xv = (float)xh[c] + (float)xl[c];
    nn += xv * xv;
    float4 s0 = ((const float4*)sim)[c*2];
    float4 s1 = ((const float4*)sim)[c*2+1];
    float sv[8] = {s0.x,s0.y,s0.z,s0.w,s1.x,s1.y,s1.z,s1.w};
    #pragma unroll
    for (int e = 0; e < 8; ++e) { acc[e] += xv * sv[e]; sn2[e] += sv[e]*sv[e]; }
  }
  #pragma unroll
  for (int o = 32; o > 0; o >>= 1) {
    nn += __shfl_down(nn, o);
    #pragma unroll
    for (int e = 0; e < 8; ++e) {
      acc[e] += __shfl_down(acc[e], o);
      sn2[e] += __shfl_down(sn2[e], o);
    }
  }
  if (lane == 0) {
    float invn = 1.f / fmaxf(sqrtf(nn), 1e-12f);
    float logits[8], gated[8], mask[8];
    int act = 0;
    #pragma unroll
    for (int e = 0; e < 8; ++e) {
      float invs = 1.f / fmaxf(sqrtf(sn2[e]), 1e-12f);
      float sg = 1.f / (1.f + expf(-gates[e]));
      float lg = acc[e] * invn * invs - sg;
      logits[e] = lg;
      gated[e] = fmaxf(lg, 0.f);
      mask[e] = (gated[e] > 0.f) ? 1.f : 0.f;
      act += (gated[e] > 0.f) ? 1 : 0;
    }
    if (act == 0) {  // forced top-2 (first-index tie semantics like lax.top_k)
      int i1 = 0;
      #pragma unroll
      for (int e = 1; e < 8; ++e) if (logits[e] > logits[i1]) i1 = e;
      int i2 = (i1 == 0) ? 1 : 0;
      #pragma unroll
      for (int e = 0; e < 8; ++e) if (e != i1 && e != i2 && logits[e] > logits[i2]) i2 = e;
      mask[i1] = 1.f; mask[i2] = 1.f;
    }
    float mx = -3.4e38f;
    #pragma unroll
    for (int e = 0; e < 8; ++e) if (mask[e] > 0.f) mx = fmaxf(mx, gated[e]);
    float ssum = 0.f, p[8];
    #pragma unroll
    for (int e = 0; e < 8; ++e) { p[e] = (mask[e] > 0.f) ? expf(gated[e] - mx) : 0.f; ssum += p[e]; }
    float inv = 1.f / ssum;
    #pragma unroll
    for (int e = 0; e < 8; ++e) rw[(size_t)t*8 + e] = p[e] * inv;
  }
}

// ------------- transpose + (optional) bf16 split: out[j][i] = src[i][j] -----
__global__ __launch_bounds__(256) void transpose_split(
    const float* __restrict__ src, bf16* __restrict__ dsth, bf16* __restrict__ dstl,
    int ldsrc, int lddst, long sBatch, long dBatch)
{
  __shared__ float tile[32][33];
  src  += (size_t)blockIdx.z * sBatch;
  dsth += (size_t)blockIdx.z * dBatch;
  if (dstl) dstl += (size_t)blockIdx.z * dBatch;
  int j0 = blockIdx.x * 32;   // src col
  int i0 = blockIdx.y * 32;   // src row
  int tx = threadIdx.x & 31, ty = threadIdx.x >> 5;
  #pragma unroll
  for (int r = 0; r < 32; r += 8)
    tile[ty + r][tx] = src[(size_t)(i0 + ty + r) * ldsrc + j0 + tx];
  __syncthreads();
  #pragma unroll
  for (int r = 0; r < 32; r += 8) {
    float v = tile[tx][ty + r];
    size_t o = (size_t)(j0 + ty + r) * lddst + i0 + tx;
    bf16 hh, ll; split2(v, hh, ll);
    dsth[o] = hh;
    if (dstl) dstl[o] = ll;
  }
}

// ---------------- GEMM: C(MxN) = A(MxK) * B^T(NxK), bf16 mfma ---------------
// SPLIT: hi/lo bf16 pair inputs (3 mfma/product).
// EPI: 0 f32 store | 1 f32 +res | 2 gelu*rw -> bf16 | 3 split-bf16 (v*scale)
//      | 4 f32 atomicAdd (for split-K)
// CAUSAL: skip tiles with n0 > m0.
// KSPLIT: blockIdx.z = bz*KSPLIT + kchunk; each chunk does K/KSPLIT.
template<int SPLIT, int EPI, int CAUSAL, int KSPLIT>
__global__ __launch_bounds__(256) void gemm_kernel(
    const bf16* __restrict__ Ah, const bf16* __restrict__ Al,
    const bf16* __restrict__ Bh, const bf16* __restrict__ Bl,
    float* __restrict__ Co, const float* __restrict__ res,
    const float* __restrict__ rwp, bf16* __restrict__ outb,
    bf16* __restrict__ outb2, float scale,
    int M, int N, int K, long aB, long bB, long cB)
{
  int n0 = blockIdx.x * 128, m0 = blockIdx.y * 128;
  if (CAUSAL && n0 > m0) return;
  int bz = (KSPLIT > 1) ? (blockIdx.z / KSPLIT) : blockIdx.z;
  int kc0 = 0, kc1 = K;
  if constexpr (KSPLIT > 1) {
    int kch = blockIdx.z % KSPLIT;
    int Kc = K / KSPLIT;
    kc0 = kch * Kc; kc1 = kc0 + Kc;
  }
  const bf16* aH = Ah + (size_t)bz * aB + (size_t)m0 * K;
  const bf16* bH = Bh + (size_t)bz * bB + (size_t)n0 * K;
  const bf16* aL = nullptr; const bf16* bL = nullptr;
  if constexpr (SPLIT) {
    aL = Al + (size_t)bz * aB + (size_t)m0 * K;
    bL = Bl + (size_t)bz * bB + (size_t)n0 * K;
  }
  __shared__ bf16 As[SPLIT + 1][128 * 32];
  __shared__ bf16 Bs[SPLIT + 1][128 * 32];
  const f32x4 fz = {0.f, 0.f, 0.f, 0.f};
  f32x4 acc[4][4];
  #pragma unroll
  for (int i = 0; i < 4; ++i)
    #pragma unroll
    for (int j = 0; j < 4; ++j) acc[i][j] = fz;

  int lane = threadIdx.x & 63;
  int wv = threadIdx.x >> 6;
  int wr = wv >> 1, wc = wv & 1;
  int l15 = lane & 15;
  int kOff = (lane >> 4) * 8;
  int t = threadIdx.x;

  for (int k0 = kc0; k0 < kc1; k0 += 32) {
    #pragma unroll
    for (int cch = 0; cch < 2; ++cch) {
      int ci = t + cch * 256;
      int row = ci >> 2;
      int kc = (ci & 3) * 8;
      size_t go = (size_t)row * K + (size_t)(k0 + kc);
      __builtin_amdgcn_global_load_lds(GLBP(aH + go), LDSP(&As[0][ci * 8]), 16, 0, 0);
      __builtin_amdgcn_global_load_lds(GLBP(bH + go), LDSP(&Bs[0][ci * 8]), 16, 0, 0);
      if constexpr (SPLIT) {
        __builtin_amdgcn_global_load_lds(GLBP(aL + go), LDSP(&As[1][ci * 8]), 16, 0, 0);
        __builtin_amdgcn_global_load_lds(GLBP(bL + go), LDSP(&Bs[1][ci * 8]), 16, 0, 0);
      }
    }
    __syncthreads();
    bf16x8 aF[2][4], bF[2][4];
    #pragma unroll
    for (int i = 0; i < 4; ++i) {
      aF[0][i] = *(const bf16x8*)&As[0][(wr*64 + i*16 + l15) * 32 + kOff];
      bF[0][i] = *(const bf16x8*)&Bs[0][(wc*64 + i*16 + l15) * 32 + kOff];
      if constexpr (SPLIT) {
        aF[1][i] = *(const bf16x8*)&As[1][(wr*64 + i*16 + l15) * 32 + kOff];
        bF[1][i] = *(const bf16x8*)&Bs[1][(wc*64 + i*16 + l15) * 32 + kOff];
      }
    }
    #pragma unroll
    for (int i = 0; i < 4; ++i)
      #pragma unroll
      for (int j = 0; j < 4; ++j) {
        acc[i][j] = __builtin_amdgcn_mfma_f32_16x16x32_bf16(aF[0][i], bF[0][j], acc[i][j], 0, 0, 0);
        if constexpr (SPLIT) {
          acc[i][j] = __builtin_amdgcn_mfma_f32_16x16x32_bf16(aF[0][i], bF[1][j], acc[i][j], 0, 0, 0);
          acc[i][j] = __builtin_amdgcn_mfma_f32_16x16x32_bf16(aF[1][i], bF[0][j], acc[i][j], 0, 0, 0);
        }
      }
    __syncthreads();
  }

  size_t cz = (size_t)bz * cB;
  #pragma unroll
  for (int i = 0; i < 4; ++i) {
    #pragma unroll
    for (int j = 0; j < 4; ++j) {
      int r0 = m0 + wr*64 + i*16 + (lane >> 4) * 4;
      int ccol = n0 + wc*64 + j*16 + l15;
      #pragma unroll
      for (int jj = 0; jj < 4; ++jj) {
        float v = acc[i][j][jj];
        size_t idx = cz + (size_t)(r0 + jj) * N + ccol;
        if constexpr (EPI == 0) {
          Co[idx] = v;
        } else if constexpr (EPI == 1) {
          Co[idx] = v + res[idx];
        } else if constexpr (EPI == 2) {
          float gl = 0.5f * v * (1.f + erff(v * 0.70710678118654752f));
          float wgt = rwp[(size_t)(r0 + jj) * 8 + (ccol >> 10)];
          outb[idx] = (bf16)(gl * wgt);
        } else if constexpr (EPI == 3) {
          split2(v * scale, outb[idx], outb2[idx]);
        } else {
          unsafeAtomicAdd(&Co[idx], v);
        }
      }
    }
  }
}

// ---------------- per-token expert reduce of QKV ----------------------------
__global__ __launch_bounds__(128) void qkv_reduce_kernel(
    const float* __restrict__ qkv, const float* __restrict__ rw,
    bf16* __restrict__ qh, bf16* __restrict__ ql,
    bf16* __restrict__ kh, bf16* __restrict__ kl,
    float* __restrict__ vf)
{
  int t = blockIdx.x, sel = blockIdx.y, h = threadIdx.x;
  const float* src = qkv + (size_t)t * 3072 + sel * 1024 + h;
  const float* rp = rw + (size_t)t * 8;
  float acc = 0.f;
  #pragma unroll
  for (int e = 0; e < 8; ++e) acc += rp[e] * src[e * 128];
  size_t o = (size_t)t * HD + h;
  if (sel == 0)      split2(acc, qh[o], ql[o]);
  else if (sel == 1) split2(acc, kh[o], kl[o]);
  else               vf[o] = acc;
}

// ------- causal softmax, IN-PLACE over split-bf16 scores -> split-bf16 P ----
__global__ __launch_bounds__(256) void softmax_kernel(
    bf16* __restrict__ ph, bf16* __restrict__ pl)
{
  __shared__ float sm[4];
  int t = blockIdx.x;
  size_t ro = ((size_t)blockIdx.y * TS + t) * TS;
  float vals[8];
  float mx = -3.4e38f;
  #pragma unroll
  for (int u = 0; u < 8; ++u) {
    int j = threadIdx.x + u * 256;
    float v = (j <= t) ? ((float)ph[ro + j] + (float)pl[ro + j]) : -3.4e38f;
    vals[u] = v;
    mx = fmaxf(mx, v);
  }
  mx = blk_max(mx, sm);
  float sum = 0.f;
  #pragma unroll
  for (int u = 0; u < 8; ++u) {
    int j = threadIdx.x + u * 256;
    float e = (j <= t) ? expf(vals[u] - mx) : 0.f;
    vals[u] = e;
    sum += e;
  }
  sum = blk_sum(sum, sm);
  float inv = 1.f / sum;
  #pragma unroll
  for (int u = 0; u < 8; ++u) {
    int j = threadIdx.x + u * 256;
    split2(vals[u] * inv, ph[ro + j], pl[ro + j]);
  }
}

// ------------- expand: A'[t][e*128+h] = rw[t][e]*attn[t][h] (split) ---------
__global__ __launch_bounds__(256) void expand_kernel(
    const float* __restrict__ attn, const float* __restrict__ rw,
    bf16* __restrict__ ah, bf16* __restrict__ al)
{
  size_t i = (size_t)blockIdx.x * 256 + threadIdx.x;
  int t = (int)(i >> 10), col = (int)(i & 1023);
  int e = col >> 7, h = col & 127;
  float v = rw[(size_t)t*8 + e] * attn[(size_t)t*HD + h];
  split2(v, ah[i], al[i]);
}

// ============================================================================
extern "C" void kernel_launch(void* const* d_in, const int* in_sizes, int n_in,
                              void* d_out, int out_size, void* d_ws, size_t ws_size,
                              hipStream_t stream) {
  const float* x        = (const float*)d_in[0];
  const float* ln1w     = (const float*)d_in[1];
  const float* ln1b     = (const float*)d_in[2];
  const float* ln2w     = (const float*)d_in[3];
  const float* ln2b     = (const float*)d_in[4];
  const float* smha_sim = (const float*)d_in[5];
  const float* smha_g   = (const float*)d_in[6];
  const float* q_proj   = (const float*)d_in[7];
  const float* k_proj   = (const float*)d_in[8];
  const float* v_proj   = (const float*)d_in[9];
  const float* o_proj   = (const float*)d_in[10];
  const float* moe_sim  = (const float*)d_in[11];
  const float* moe_g    = (const float*)d_in[12];
  const float* w1       = (const float*)d_in[13];
  const float* w2       = (const float*)d_in[14];
  float* out = (float*)d_out;
  (void)in_sizes; (void)n_in; (void)out_size;

  // ---- workspace layout (227 MB peak, phase-aliased arenas) ----
  char* ws = (char*)d_ws;
  size_t off = 0;
  auto alloc = [&](size_t bytes) -> char* {
    char* p = ws + off;
    off += (bytes + 255) & ~(size_t)255;
    return p;
  };
  float* hs    = (float*)alloc(33554432);   // (8192,1024) f32      [live: O-proj -> end]
  bf16*  n1h   = (bf16*) alloc(16777216);   // split LN out         [LN1->QKV, LN2->MoE]
  bf16*  n1l   = (bf16*) alloc(16777216);
  float* rwA   = (float*)alloc(262144);
  float* rwM   = (float*)alloc(262144);
  bf16*  OtH   = (bf16*) alloc(2097152);
  bf16*  OtL   = (bf16*) alloc(2097152);
  bf16*  qh    = (bf16*) alloc(2097152);
  bf16*  ql    = (bf16*) alloc(2097152);
  bf16*  kh    = (bf16*) alloc(2097152);
  bf16*  kl    = (bf16*) alloc(2097152);
  float* vf    = (float*)alloc(4194304);
  bf16*  vth   = (bf16*) alloc(2097152);
  bf16*  vtl   = (bf16*) alloc(2097152);
  float* attnH = (float*)alloc(4194304);
  char*  segW  = alloc(33554432);           // Wqkv split | W1t+W2t
  char*  segB  = alloc(100663296);          // qkvAll | scores/P split | Ae split | interH
  size_t NEED = off;
  if (ws_size < NEED) return;  // constant per-call; yields clean numeric-fail diagnostic

  bf16* WqkvH = (bf16*)segW;                      // 3072x1024
  bf16* WqkvL = (bf16*)(segW + 6291456);
  bf16* W1t   = (bf16*)segW;                      // 8192x1024
  bf16* W2t   = (bf16*)(segW + 16777216);         // 1024x8192
  float* qkvAll = (float*)segB;                   // 8192x3072 f32
  bf16* Ph    = (bf16*)segB;                      // 4x2048x2048 (scores then P, in-place)
  bf16* Pl    = (bf16*)(segB + 33554432);
  bf16* Aeh   = (bf16*)segB;                      // 8192x1024
  bf16* Ael   = (bf16*)(segB + 16777216);
  bf16* interH= (bf16*)segB;                      // 4096x8192 (per M-half, 67MB)

  // ---- attention weights: transpose + split ----
  transpose_split<<<dim3(4, 32, 8), 256, 0, stream>>>(q_proj, WqkvH, WqkvL, 128, 1024, 131072L, 131072L);
  transpose_split<<<dim3(4, 32, 8), 256, 0, stream>>>(k_proj, WqkvH + 1048576, WqkvL + 1048576, 128, 1024, 131072L, 131072L);
  transpose_split<<<dim3(4, 32, 8), 256, 0, stream>>>(v_proj, WqkvH + 2097152, WqkvL + 2097152, 128, 1024, 131072L, 131072L);
  transpose_split<<<dim3(32, 4, 8), 256, 0, stream>>>(o_proj, OtH, OtL, 1024, 1024, 131072L, 128L);

  // ---- LN1 + attention gating ----
  ln_kernel<<<NTOK, 256, 0, stream>>>(x, ln1w, ln1b, n1h, n1l);
  gating_kernel<<<NTOK / 4, 256, 0, stream>>>(n1h, n1l, smha_sim, smha_g, rwA);

  // ---- QKV all-expert GEMM (split) + rw reduce ----
  gemm_kernel<1, 0, 0, 1><<<dim3(24, 64, 1), 256, 0, stream>>>(
      n1h, n1l, WqkvH, WqkvL, qkvAll, nullptr, nullptr, nullptr, nullptr, 1.f,
      NTOK, 3072, CD, 0L, 0L, 0L);
  qkv_reduce_kernel<<<dim3(NTOK, 3), 128, 0, stream>>>(qkvAll, rwA, qh, ql, kh, kl, vf);
  transpose_split<<<dim3(4, 64, 4), 256, 0, stream>>>(vf, vth, vtl, 128, 2048, 262144L, 262144L);

  // ---- attention: scores (split-bf16, scale folded), softmax in-place, PV --
  gemm_kernel<1, 3, 1, 1><<<dim3(16, 16, 4), 256, 0, stream>>>(
      qh, ql, kh, kl, nullptr, nullptr, nullptr, Ph, Pl, 0.08838834764831845f,
      TS, TS, HD, (long)TS * HD, (long)TS * HD, (long)TS * TS);
  softmax_kernel<<<dim3(TS, NB), 256, 0, stream>>>(Ph, Pl);
  // PV with split-K=4 into zeroed attnH (grid 256 wg instead of 64)
  hipMemsetAsync(attnH, 0, 4194304, stream);
  gemm_kernel<1, 4, 0, 4><<<dim3(1, 16, 16), 256, 0, stream>>>(
      Ph, Pl, vth, vtl, attnH, nullptr, nullptr, nullptr, nullptr, 1.f,
      TS, HD, TS, (long)TS * TS, (long)HD * TS, (long)TS * HD);

  // ---- O-projection with rw folded into A, +x residual -> hs ----
  expand_kernel<<<NTOK * CD / 256, 256, 0, stream>>>(attnH, rwA, Aeh, Ael);
  gemm_kernel<1, 1, 0, 1><<<dim3(8, 64, 1), 256, 0, stream>>>(
      Aeh, Ael, OtH, OtL, hs, x, nullptr, nullptr, nullptr, 1.f,
      NTOK, CD, CD, 0L, 0L, 0L);

  // ---- LN2 + MoE gating ----
  ln_kernel<<<NTOK, 256, 0, stream>>>(hs, ln2w, ln2b, n1h, n1l);  // n2 split
  gating_kernel<<<NTOK / 4, 256, 0, stream>>>(n1h, n1l, moe_sim, moe_g, rwM);

  // ---- MoE weights (plain bf16) ----
  transpose_split<<<dim3(32, 32, 8), 256, 0, stream>>>(w1, W1t, nullptr, 1024, 1024, 1048576L, 1048576L);
  transpose_split<<<dim3(32, 32, 8), 256, 0, stream>>>(w2, W2t, nullptr, 1024, 8192, 1048576L, 1024L);

  // ---- out = hs (residual base), then MoE adds into it atomically ----
  hipMemcpyAsync(out, hs, 33554432, hipMemcpyDeviceToDevice, stream);

  // ---- MoE in 2 M-halves; GEMM2 split-K=4 (1024 wg) atomic into out ----
  for (int h = 0; h < 2; ++h) {
    gemm_kernel<0, 2, 0, 1><<<dim3(64, 32, 1), 256, 0, stream>>>(
        n1h + (size_t)h * 4194304, nullptr, W1t, nullptr,
        nullptr, nullptr, rwM + (size_t)h * 32768, interH, nullptr, 1.f,
        4096, 8192, CD, 0L, 0L, 0L);
    gemm_kernel<0, 4, 0, 4><<<dim3(8, 32, 4), 256, 0, stream>>>(
        interH, nullptr, W2t, nullptr,
        out + (size_t)h * 4194304, nullptr, nullptr, nullptr, nullptr, 1.f,
        4096, CD, 8192, 0L, 0L, 0L);
  }
}

// Round 6
// 1099.694 us; speedup vs baseline: 1.4382x; 1.0008x over previous
//
#include <hip/hip_runtime.h>
#include <math.h>

typedef __bf16 bf16;
typedef __attribute__((ext_vector_type(8))) __bf16 bf16x8;
typedef __attribute__((ext_vector_type(4))) float f32x4;

#define LDSP(p) ((__attribute__((address_space(3))) void*)(p))
#define GLBP(p) ((const __attribute__((address_space(1))) void*)(p))

static constexpr int NTOK = 8192;   // B*T
static constexpr int CD   = 1024;   // C
static constexpr int HD   = 128;    // head dim
static constexpr int TS   = 2048;   // T
static constexpr int NB   = 4;      // B
static constexpr int CAP  = 8192;   // per-expert token capacity (hard bound)

__device__ __forceinline__ void split2(float x, bf16& h, bf16& l) {
  bf16 hh = (bf16)x;
  h = hh;
  l = (bf16)(x - (float)hh);
}

__device__ __forceinline__ float blk_sum(float v, float* sm) {
  #pragma unroll
  for (int o = 32; o > 0; o >>= 1) v += __shfl_down(v, o);
  if ((threadIdx.x & 63) == 0) sm[threadIdx.x >> 6] = v;
  __syncthreads();
  v = sm[0] + sm[1] + sm[2] + sm[3];
  __syncthreads();
  return v;
}

__device__ __forceinline__ float blk_max(float v, float* sm) {
  #pragma unroll
  for (int o = 32; o > 0; o >>= 1) v = fmaxf(v, __shfl_down(v, o));
  if ((threadIdx.x & 63) == 0) sm[threadIdx.x >> 6] = v;
  __syncthreads();
  v = fmaxf(fmaxf(sm[0], sm[1]), fmaxf(sm[2], sm[3]));
  __syncthreads();
  return v;
}

// ---------------- LayerNorm: bf16 hi/lo split out ---------------------------
__global__ __launch_bounds__(256) void ln_kernel(
    const float* __restrict__ x, const float* __restrict__ w, const float* __restrict__ b,
    bf16* __restrict__ outh, bf16* __restrict__ outl)
{
  __shared__ float sm[4];
  size_t ro = (size_t)blockIdx.x * CD;
  float4 v = ((const float4*)(x + ro))[threadIdx.x];
  float s = v.x + v.y + v.z + v.w;
  s = blk_sum(s, sm);
  float mean = s * (1.f / CD);
  float dx = v.x - mean, dy = v.y - mean, dz = v.z - mean, dw = v.w - mean;
  float sq = dx*dx + dy*dy + dz*dz + dw*dw;
  sq = blk_sum(sq, sm);
  float rstd = rsqrtf(sq * (1.f / CD) + 1e-5f);
  float4 wv = ((const float4*)w)[threadIdx.x];
  float4 bv = ((const float4*)b)[threadIdx.x];
  float y0 = dx*rstd*wv.x + bv.x, y1 = dy*rstd*wv.y + bv.y;
  float y2 = dz*rstd*wv.z + bv.z, y3 = dw*rstd*wv.w + bv.w;
  size_t c0 = ro + (size_t)threadIdx.x * 4;
  split2(y0, outh[c0+0], outl[c0+0]);
  split2(y1, outh[c0+1], outl[c0+1]);
  split2(y2, outh[c0+2], outl[c0+2]);
  split2(y3, outh[c0+3], outl[c0+3]);
}

// ------- Gating: one wave per token; also builds per-expert token lists -----
__global__ __launch_bounds__(256) void gating_kernel(
    const bf16* __restrict__ nh, const bf16* __restrict__ nl,
    const float* __restrict__ sim, const float* __restrict__ gates,
    float* __restrict__ rw, int* __restrict__ idxL, int* __restrict__ cnt)
{
  int t = blockIdx.x * 4 + (threadIdx.x >> 6);
  int lane = threadIdx.x & 63;
  const bf16* xh = nh + (size_t)t * CD;
  const bf16* xl = nl + (size_t)t * CD;
  float acc[8] = {0,0,0,0,0,0,0,0};
  float sn2[8] = {0,0,0,0,0,0,0,0};
  float nn = 0.f;
  for (int c = lane; c < CD; c += 64) {
    float xv = (float)xh[c] + (float)xl[c];
    nn += xv * xv;
    float4 s0 = ((const float4*)sim)[c*2];
    float4 s1 = ((const float4*)sim)[c*2+1];
    float sv[8] = {s0.x,s0.y,s0.z,s0.w,s1.x,s1.y,s1.z,s1.w};
    #pragma unroll
    for (int e = 0; e < 8; ++e) { acc[e] += xv * sv[e]; sn2[e] += sv[e]*sv[e]; }
  }
  #pragma unroll
  for (int o = 32; o > 0; o >>= 1) {
    nn += __shfl_down(nn, o);
    #pragma unroll
    for (int e = 0; e < 8; ++e) {
      acc[e] += __shfl_down(acc[e], o);
      sn2[e] += __shfl_down(sn2[e], o);
    }
  }
  if (lane == 0) {
    float invn = 1.f / fmaxf(sqrtf(nn), 1e-12f);
    float logits[8], gated[8], mask[8];
    int act = 0;
    #pragma unroll
    for (int e = 0; e < 8; ++e) {
      float invs = 1.f / fmaxf(sqrtf(sn2[e]), 1e-12f);
      float sg = 1.f / (1.f + expf(-gates[e]));
      float lg = acc[e] * invn * invs - sg;
      logits[e] = lg;
      gated[e] = fmaxf(lg, 0.f);
      mask[e] = (gated[e] > 0.f) ? 1.f : 0.f;
      act += (gated[e] > 0.f) ? 1 : 0;
    }
    if (act == 0) {  // forced top-2 (first-index tie semantics like lax.top_k)
      int i1 = 0;
      #pragma unroll
      for (int e = 1; e < 8; ++e) if (logits[e] > logits[i1]) i1 = e;
      int i2 = (i1 == 0) ? 1 : 0;
      #pragma unroll
      for (int e = 0; e < 8; ++e) if (e != i1 && e != i2 && logits[e] > logits[i2]) i2 = e;
      mask[i1] = 1.f; mask[i2] = 1.f;
    }
    float mx = -3.4e38f;
    #pragma unroll
    for (int e = 0; e < 8; ++e) if (mask[e] > 0.f) mx = fmaxf(mx, gated[e]);
    float ssum = 0.f, p[8];
    #pragma unroll
    for (int e = 0; e < 8; ++e) { p[e] = (mask[e] > 0.f) ? expf(gated[e] - mx) : 0.f; ssum += p[e]; }
    float inv = 1.f / ssum;
    #pragma unroll
    for (int e = 0; e < 8; ++e) {
      float pv = p[e] * inv;
      rw[(size_t)t*8 + e] = pv;
      if (pv > 0.f) {
        int pos = atomicAdd(&cnt[e], 1);
        idxL[(size_t)e * CAP + pos] = t;
      }
    }
  }
}

// ------------- transpose + (optional) bf16 split: out[j][i] = src[i][j] -----
__global__ __launch_bounds__(256) void transpose_split(
    const float* __restrict__ src, bf16* __restrict__ dsth, bf16* __restrict__ dstl,
    int ldsrc, int lddst, long sBatch, long dBatch)
{
  __shared__ float tile[32][33];
  src  += (size_t)blockIdx.z * sBatch;
  dsth += (size_t)blockIdx.z * dBatch;
  if (dstl) dstl += (size_t)blockIdx.z * dBatch;
  int j0 = blockIdx.x * 32;   // src col
  int i0 = blockIdx.y * 32;   // src row
  int tx = threadIdx.x & 31, ty = threadIdx.x >> 5;
  #pragma unroll
  for (int r = 0; r < 32; r += 8)
    tile[ty + r][tx] = src[(size_t)(i0 + ty + r) * ldsrc + j0 + tx];
  __syncthreads();
  #pragma unroll
  for (int r = 0; r < 32; r += 8) {
    float v = tile[tx][ty + r];
    size_t o = (size_t)(j0 + ty + r) * lddst + i0 + tx;
    bf16 hh, ll; split2(v, hh, ll);
    dsth[o] = hh;
    if (dstl) dstl[o] = ll;
  }
}

// -------- dense GEMM (for attention scores / PV), as verified in R5 ---------
// EPI: 3 split-bf16 (v*scale) | 4 f32 atomicAdd. CAUSAL skip. KSPLIT chunks.
template<int SPLIT, int EPI, int CAUSAL, int KSPLIT>
__global__ __launch_bounds__(256) void gemm_kernel(
    const bf16* __restrict__ Ah, const bf16* __restrict__ Al,
    const bf16* __restrict__ Bh, const bf16* __restrict__ Bl,
    float* __restrict__ Co, bf16* __restrict__ outb,
    bf16* __restrict__ outb2, float scale,
    int M, int N, int K, long aB, long bB, long cB)
{
  int n0 = blockIdx.x * 128, m0 = blockIdx.y * 128;
  if (CAUSAL && n0 > m0) return;
  int bz = (KSPLIT > 1) ? (blockIdx.z / KSPLIT) : blockIdx.z;
  int kc0 = 0, kc1 = K;
  if constexpr (KSPLIT > 1) {
    int kch = blockIdx.z % KSPLIT;
    int Kc = K / KSPLIT;
    kc0 = kch * Kc; kc1 = kc0 + Kc;
  }
  const bf16* aH = Ah + (size_t)bz * aB + (size_t)m0 * K;
  const bf16* bH = Bh + (size_t)bz * bB + (size_t)n0 * K;
  const bf16* aL = nullptr; const bf16* bL = nullptr;
  if constexpr (SPLIT) {
    aL = Al + (size_t)bz * aB + (size_t)m0 * K;
    bL = Bl + (size_t)bz * bB + (size_t)n0 * K;
  }
  __shared__ bf16 As[SPLIT + 1][128 * 32];
  __shared__ bf16 Bs[SPLIT + 1][128 * 32];
  const f32x4 fz = {0.f, 0.f, 0.f, 0.f};
  f32x4 acc[4][4];
  #pragma unroll
  for (int i = 0; i < 4; ++i)
    #pragma unroll
    for (int j = 0; j < 4; ++j) acc[i][j] = fz;

  int lane = threadIdx.x & 63;
  int wv = threadIdx.x >> 6;
  int wr = wv >> 1, wc = wv & 1;
  int l15 = lane & 15;
  int kOff = (lane >> 4) * 8;
  int tt = threadIdx.x;

  for (int k0 = kc0; k0 < kc1; k0 += 32) {
    #pragma unroll
    for (int cch = 0; cch < 2; ++cch) {
      int ci = tt + cch * 256;
      int row = ci >> 2;
      int kc = (ci & 3) * 8;
      size_t go = (size_t)row * K + (size_t)(k0 + kc);
      __builtin_amdgcn_global_load_lds(GLBP(aH + go), LDSP(&As[0][ci * 8]), 16, 0, 0);
      __builtin_amdgcn_global_load_lds(GLBP(bH + go), LDSP(&Bs[0][ci * 8]), 16, 0, 0);
      if constexpr (SPLIT) {
        __builtin_amdgcn_global_load_lds(GLBP(aL + go), LDSP(&As[1][ci * 8]), 16, 0, 0);
        __builtin_amdgcn_global_load_lds(GLBP(bL + go), LDSP(&Bs[1][ci * 8]), 16, 0, 0);
      }
    }
    __syncthreads();
    bf16x8 aF[2][4], bF[2][4];
    #pragma unroll
    for (int i = 0; i < 4; ++i) {
      aF[0][i] = *(const bf16x8*)&As[0][(wr*64 + i*16 + l15) * 32 + kOff];
      bF[0][i] = *(const bf16x8*)&Bs[0][(wc*64 + i*16 + l15) * 32 + kOff];
      if constexpr (SPLIT) {
        aF[1][i] = *(const bf16x8*)&As[1][(wr*64 + i*16 + l15) * 32 + kOff];
        bF[1][i] = *(const bf16x8*)&Bs[1][(wc*64 + i*16 + l15) * 32 + kOff];
      }
    }
    #pragma unroll
    for (int i = 0; i < 4; ++i)
      #pragma unroll
      for (int j = 0; j < 4; ++j) {
        acc[i][j] = __builtin_amdgcn_mfma_f32_16x16x32_bf16(aF[0][i], bF[0][j], acc[i][j], 0, 0, 0);
        if constexpr (SPLIT) {
          acc[i][j] = __builtin_amdgcn_mfma_f32_16x16x32_bf16(aF[0][i], bF[1][j], acc[i][j], 0, 0, 0);
          acc[i][j] = __builtin_amdgcn_mfma_f32_16x16x32_bf16(aF[1][i], bF[0][j], acc[i][j], 0, 0, 0);
        }
      }
    __syncthreads();
  }

  size_t cz = (size_t)bz * cB;
  #pragma unroll
  for (int i = 0; i < 4; ++i) {
    #pragma unroll
    for (int j = 0; j < 4; ++j) {
      int r0 = m0 + wr*64 + i*16 + (lane >> 4) * 4;
      int ccol = n0 + wc*64 + j*16 + l15;
      #pragma unroll
      for (int jj = 0; jj < 4; ++jj) {
        float v = acc[i][j][jj];
        size_t idx = cz + (size_t)(r0 + jj) * N + ccol;
        if constexpr (EPI == 3) {
          split2(v * scale, outb[idx], outb2[idx]);
        } else {
          unsafeAtomicAdd(&Co[idx], v);
        }
      }
    }
  }
}

// ------ SPARSE expert GEMM: per-expert gathered rows, fixed grid ------------
// A rows: GATHER ? token-keyed via idxL : slot-keyed (per local expert block).
// B: per-expert (N x K) at Bh + e*bB. Early exit when m0 >= cnt[e].
// EPI: 0 atomic wgt*v -> outF[t*ldC+col]       (QKV accum)
//      1 atomic wgt*v -> outF[t*1024+col]      (O-proj into hs)
//      2 bf16(gelu(v)*wgt) -> outB slot-keyed  (MoE inter)
//      3 atomic v -> outF[t*1024+col]          (MoE down-proj into out)
template<int SPLIT, int EPI, int GATHER>
__global__ __launch_bounds__(256) void sgemm_kernel(
    const bf16* __restrict__ Ah, const bf16* __restrict__ Al,
    const bf16* __restrict__ Bh, const bf16* __restrict__ Bl,
    const int* __restrict__ idxL, const int* __restrict__ cnt,
    const float* __restrict__ rw, float* __restrict__ outF,
    bf16* __restrict__ outB,
    int lda, int K, int ldC, int eBase, long bB)
{
  int e = eBase + blockIdx.z;
  int count = cnt[e];
  int m0 = blockIdx.y * 128;
  if (m0 >= count) return;
  int n0 = blockIdx.x * 128;
  const int* myIdx = idxL + (size_t)e * CAP;
  const bf16* bH = Bh + (size_t)e * bB;
  const bf16* bL = nullptr;
  const bf16* aH = Ah;
  const bf16* aL = Al;
  if constexpr (SPLIT) bL = Bl + (size_t)e * bB;
  if constexpr (!GATHER) {
    aH += (size_t)blockIdx.z * CAP * lda;
    if constexpr (SPLIT) aL += (size_t)blockIdx.z * CAP * lda;
  }

  __shared__ bf16 As[SPLIT + 1][128 * 32];
  __shared__ bf16 Bs[SPLIT + 1][128 * 32];
  const f32x4 fz = {0.f, 0.f, 0.f, 0.f};
  f32x4 acc[4][4];
  #pragma unroll
  for (int i = 0; i < 4; ++i)
    #pragma unroll
    for (int j = 0; j < 4; ++j) acc[i][j] = fz;

  int lane = threadIdx.x & 63;
  int wv = threadIdx.x >> 6;
  int wr = wv >> 1, wc = wv & 1;
  int l15 = lane & 15;
  int kOff = (lane >> 4) * 8;
  int tt = threadIdx.x;

  // per-thread A-row resolution (two staging chunks), hoisted out of K-loop
  int r1 = tt >> 2;
  int kcA = (tt & 3) * 8;
  int s1 = m0 + r1, s2 = s1 + 64;
  int ga1, ga2;
  if constexpr (GATHER) {
    ga1 = myIdx[s1 < count ? s1 : count - 1];
    ga2 = myIdx[s2 < count ? s2 : count - 1];
  } else { ga1 = s1; ga2 = s2; }
  size_t ao1 = (size_t)ga1 * lda, ao2 = (size_t)ga2 * lda;
  size_t bo1 = (size_t)(n0 + r1) * K, bo2 = (size_t)(n0 + r1 + 64) * K;

  for (int k0 = 0; k0 < K; k0 += 32) {
    size_t kk = (size_t)(k0 + kcA);
    __builtin_amdgcn_global_load_lds(GLBP(aH + ao1 + kk), LDSP(&As[0][tt * 8]), 16, 0, 0);
    __builtin_amdgcn_global_load_lds(GLBP(bH + bo1 + kk), LDSP(&Bs[0][tt * 8]), 16, 0, 0);
    __builtin_amdgcn_global_load_lds(GLBP(aH + ao2 + kk), LDSP(&As[0][(tt + 256) * 8]), 16, 0, 0);
    __builtin_amdgcn_global_load_lds(GLBP(bH + bo2 + kk), LDSP(&Bs[0][(tt + 256) * 8]), 16, 0, 0);
    if constexpr (SPLIT) {
      __builtin_amdgcn_global_load_lds(GLBP(aL + ao1 + kk), LDSP(&As[1][tt * 8]), 16, 0, 0);
      __builtin_amdgcn_global_load_lds(GLBP(bL + bo1 + kk), LDSP(&Bs[1][tt * 8]), 16, 0, 0);
      __builtin_amdgcn_global_load_lds(GLBP(aL + ao2 + kk), LDSP(&As[1][(tt + 256) * 8]), 16, 0, 0);
      __builtin_amdgcn_global_load_lds(GLBP(bL + bo2 + kk), LDSP(&Bs[1][(tt + 256) * 8]), 16, 0, 0);
    }
    __syncthreads();
    bf16x8 aF[2][4], bF[2][4];
    #pragma unroll
    for (int i = 0; i < 4; ++i) {
      aF[0][i] = *(const bf16x8*)&As[0][(wr*64 + i*16 + l15) * 32 + kOff];
      bF[0][i] = *(const bf16x8*)&Bs[0][(wc*64 + i*16 + l15) * 32 + kOff];
      if constexpr (SPLIT) {
        aF[1][i] = *(const bf16x8*)&As[1][(wr*64 + i*16 + l15) * 32 + kOff];
        bF[1][i] = *(const bf16x8*)&Bs[1][(wc*64 + i*16 + l15) * 32 + kOff];
      }
    }
    #pragma unroll
    for (int i = 0; i < 4; ++i)
      #pragma unroll
      for (int j = 0; j < 4; ++j) {
        acc[i][j] = __builtin_amdgcn_mfma_f32_16x16x32_bf16(aF[0][i], bF[0][j], acc[i][j], 0, 0, 0);
        if constexpr (SPLIT) {
          acc[i][j] = __builtin_amdgcn_mfma_f32_16x16x32_bf16(aF[0][i], bF[1][j], acc[i][j], 0, 0, 0);
          acc[i][j] = __builtin_amdgcn_mfma_f32_16x16x32_bf16(aF[1][i], bF[0][j], acc[i][j], 0, 0, 0);
        }
      }
    __syncthreads();
  }

  #pragma unroll
  for (int i = 0; i < 4; ++i) {
    #pragma unroll
    for (int jj = 0; jj < 4; ++jj) {
      int sl = m0 + wr*64 + i*16 + (lane >> 4) * 4 + jj;
      if (sl >= count) continue;
      int tok = myIdx[sl];
      float wgt = 0.f;
      if constexpr (EPI <= 2) wgt = rw[(size_t)tok * 8 + e];
      #pragma unroll
      for (int j = 0; j < 4; ++j) {
        int ccol = n0 + wc*64 + j*16 + l15;
        float v = acc[i][j][jj];
        if constexpr (EPI == 0) {
          unsafeAtomicAdd(&outF[(size_t)tok * ldC + ccol], wgt * v);
        } else if constexpr (EPI == 1) {
          unsafeAtomicAdd(&outF[(size_t)tok * 1024 + ccol], wgt * v);
        } else if constexpr (EPI == 2) {
          float gl = 0.5f * v * (1.f + erff(v * 0.70710678118654752f));
          outB[((size_t)blockIdx.z * CAP + sl) * 1024 + ccol] = (bf16)(gl * wgt);
        } else {
          unsafeAtomicAdd(&outF[(size_t)tok * 1024 + ccol], v);
        }
      }
    }
  }
}

// ------- causal softmax, IN-PLACE over split-bf16 scores -> split-bf16 P ----
__global__ __launch_bounds__(256) void softmax_kernel(
    bf16* __restrict__ ph, bf16* __restrict__ pl)
{
  __shared__ float sm[4];
  int t = blockIdx.x;
  size_t ro = ((size_t)blockIdx.y * TS + t) * TS;
  float vals[8];
  float mx = -3.4e38f;
  #pragma unroll
  for (int u = 0; u < 8; ++u) {
    int j = threadIdx.x + u * 256;
    float v = (j <= t) ? ((float)ph[ro + j] + (float)pl[ro + j]) : -3.4e38f;
    vals[u] = v;
    mx = fmaxf(mx, v);
  }
  mx = blk_max(mx, sm);
  float sum = 0.f;
  #pragma unroll
  for (int u = 0; u < 8; ++u) {
    int j = threadIdx.x + u * 256;
    float e = (j <= t) ? expf(vals[u] - mx) : 0.f;
    vals[u] = e;
    sum += e;
  }
  sum = blk_sum(sum, sm);
  float inv = 1.f / sum;
  #pragma unroll
  for (int u = 0; u < 8; ++u) {
    int j = threadIdx.x + u * 256;
    split2(vals[u] * inv, ph[ro + j], pl[ro + j]);
  }
}

// ------- qkv convert: fp32 accum (8192x384) -> split q,k + fp32 v -----------
__global__ __launch_bounds__(256) void qkv_cvt(
    const float* __restrict__ qkvF,
    bf16* __restrict__ qh, bf16* __restrict__ ql,
    bf16* __restrict__ kh, bf16* __restrict__ kl,
    float* __restrict__ vf)
{
  size_t i = (size_t)blockIdx.x * 256 + threadIdx.x;   // over 8192*128
  int t = (int)(i >> 7), h = (int)(i & 127);
  const float* row = qkvF + (size_t)t * 384;
  split2(row[h], qh[i], ql[i]);
  split2(row[128 + h], kh[i], kl[i]);
  vf[i] = row[256 + h];
}

// ------- attn split: fp32 attn (8192x128) -> split bf16 ---------------------
__global__ __launch_bounds__(256) void attn_split(
    const float* __restrict__ a, bf16* __restrict__ ah, bf16* __restrict__ al)
{
  size_t i = (size_t)blockIdx.x * 256 + threadIdx.x;
  split2(a[i], ah[i], al[i]);
}

// ============================================================================
extern "C" void kernel_launch(void* const* d_in, const int* in_sizes, int n_in,
                              void* d_out, int out_size, void* d_ws, size_t ws_size,
                              hipStream_t stream) {
  const float* x        = (const float*)d_in[0];
  const float* ln1w     = (const float*)d_in[1];
  const float* ln1b     = (const float*)d_in[2];
  const float* ln2w     = (const float*)d_in[3];
  const float* ln2b     = (const float*)d_in[4];
  const float* smha_sim = (const float*)d_in[5];
  const float* smha_g   = (const float*)d_in[6];
  const float* q_proj   = (const float*)d_in[7];
  const float* k_proj   = (const float*)d_in[8];
  const float* v_proj   = (const float*)d_in[9];
  const float* o_proj   = (const float*)d_in[10];
  const float* moe_sim  = (const float*)d_in[11];
  const float* moe_g    = (const float*)d_in[12];
  const float* w1       = (const float*)d_in[13];
  const float* w2       = (const float*)d_in[14];
  float* out = (float*)d_out;
  (void)in_sizes; (void)n_in; (void)out_size;

  // ---- workspace layout (~211 MB peak) ----
  char* ws = (char*)d_ws;
  size_t off = 0;
  auto alloc = [&](size_t bytes) -> char* {
    char* p = ws + off;
    off += (bytes + 255) & ~(size_t)255;
    return p;
  };
  float* hs    = (float*)alloc(33554432);   // x + attn_out (atomic target)
  bf16*  n1h   = (bf16*) alloc(16777216);   // LN split [LN1->QKV, LN2->MoE]
  bf16*  n1l   = (bf16*) alloc(16777216);
  float* rwA   = (float*)alloc(262144);
  float* rwM   = (float*)alloc(262144);
  int*   idxA  = (int*)  alloc(262144);     // 8 x 8192 token list
  int*   idxM  = (int*)  alloc(262144);
  int*   cnts  = (int*)  alloc(256);        // [0..7] attn, [8..15] moe
  bf16*  OtH   = (bf16*) alloc(2097152);    // o_proj^T split (E,1024,128)
  bf16*  OtL   = (bf16*) alloc(2097152);
  bf16*  qh    = (bf16*) alloc(2097152);
  bf16*  ql    = (bf16*) alloc(2097152);
  bf16*  kh    = (bf16*) alloc(2097152);
  bf16*  kl    = (bf16*) alloc(2097152);
  float* vf    = (float*)alloc(4194304);
  bf16*  vth   = (bf16*) alloc(2097152);
  bf16*  vtl   = (bf16*) alloc(2097152);
  float* attnF = (float*)alloc(4194304);    // PV atomic target (8192x128 f32)
  bf16*  atth  = (bf16*) alloc(2097152);
  bf16*  attl  = (bf16*) alloc(2097152);
  float* qkvF  = (float*)alloc(12582912);   // QKV atomic accum (8192x384 f32)
  char*  segW  = alloc(33554432);           // Wqkv split (25.2MB) | W1t+W2t (33.5MB)
  char*  segB  = alloc(67108864);           // Ph+Pl (67MB) | interE group (67MB)
  size_t NEED = off;
  if (ws_size < NEED) return;

  bf16* WqkvH = (bf16*)segW;                      // (E, 384, 1024) rows q|k|v
  bf16* WqkvL = (bf16*)(segW + 12582912);
  bf16* W1t   = (bf16*)segW;                      // (E, 1024, 1024) B^T
  bf16* W2t   = (bf16*)(segW + 16777216);
  bf16* Ph    = (bf16*)segB;                      // scores then P, in-place
  bf16* Pl    = (bf16*)(segB + 33554432);
  bf16* interE= (bf16*)segB;                      // 4 experts x 8192 x 1024

  int* cntA = cnts;
  int* cntM = cnts + 8;

  // ---- zero dynamic accumulators / counters (graph-safe) ----
  hipMemsetAsync(cnts, 0, 256, stream);
  hipMemsetAsync(qkvF, 0, 12582912, stream);
  hipMemsetAsync(attnF, 0, 4194304, stream);

  // ---- attention weights: transpose + split (per-expert B^T layouts) ----
  transpose_split<<<dim3(4, 32, 8), 256, 0, stream>>>(q_proj, WqkvH,          WqkvL,          128, 1024, 131072L, 393216L);
  transpose_split<<<dim3(4, 32, 8), 256, 0, stream>>>(k_proj, WqkvH + 131072, WqkvL + 131072, 128, 1024, 131072L, 393216L);
  transpose_split<<<dim3(4, 32, 8), 256, 0, stream>>>(v_proj, WqkvH + 262144, WqkvL + 262144, 128, 1024, 131072L, 393216L);
  transpose_split<<<dim3(32, 4, 8), 256, 0, stream>>>(o_proj, OtH, OtL, 1024, 128, 131072L, 131072L);

  // ---- LN1 + attention gating (builds idxA/cntA) ----
  ln_kernel<<<NTOK, 256, 0, stream>>>(x, ln1w, ln1b, n1h, n1l);
  gating_kernel<<<NTOK / 4, 256, 0, stream>>>(n1h, n1l, smha_sim, smha_g, rwA, idxA, cntA);

  // ---- sparse QKV: per-expert gathered GEMM, atomic wgt*v into qkvF ----
  sgemm_kernel<1, 0, 1><<<dim3(3, 64, 8), 256, 0, stream>>>(
      n1h, n1l, WqkvH, WqkvL, idxA, cntA, rwA, qkvF, nullptr,
      CD, CD, 384, 0, 393216L);
  qkv_cvt<<<4096, 256, 0, stream>>>(qkvF, qh, ql, kh, kl, vf);
  transpose_split<<<dim3(4, 64, 4), 256, 0, stream>>>(vf, vth, vtl, 128, 2048, 262144L, 262144L);

  // ---- attention: scores (split, scale folded) -> softmax -> PV(split-K) ----
  gemm_kernel<1, 3, 1, 1><<<dim3(16, 16, 4), 256, 0, stream>>>(
      qh, ql, kh, kl, nullptr, Ph, Pl, 0.08838834764831845f,
      TS, TS, HD, (long)TS * HD, (long)TS * HD, (long)TS * TS);
  softmax_kernel<<<dim3(TS, NB), 256, 0, stream>>>(Ph, Pl);
  gemm_kernel<1, 4, 0, 4><<<dim3(1, 16, 16), 256, 0, stream>>>(
      Ph, Pl, vth, vtl, attnF, nullptr, nullptr, 1.f,
      TS, HD, TS, (long)TS * TS, (long)HD * TS, (long)TS * HD);

  // ---- sparse O-proj: hs = x + sum_e wgt*(attn @ Wo[e]) ----
  attn_split<<<4096, 256, 0, stream>>>(attnF, atth, attl);
  hipMemcpyAsync(hs, x, 33554432, hipMemcpyDeviceToDevice, stream);
  sgemm_kernel<1, 1, 1><<<dim3(8, 64, 8), 256, 0, stream>>>(
      atth, attl, OtH, OtL, idxA, cntA, rwA, hs, nullptr,
      HD, HD, CD, 0, 131072L);

  // ---- LN2 + MoE gating ----
  ln_kernel<<<NTOK, 256, 0, stream>>>(hs, ln2w, ln2b, n1h, n1l);  // n2 split
  gating_kernel<<<NTOK / 4, 256, 0, stream>>>(n1h, n1l, moe_sim, moe_g, rwM, idxM, cntM);

  // ---- MoE weights (plain bf16, overwrite Wqkv region) ----
  transpose_split<<<dim3(32, 32, 8), 256, 0, stream>>>(w1, W1t, nullptr, 1024, 1024, 1048576L, 1048576L);
  transpose_split<<<dim3(32, 32, 8), 256, 0, stream>>>(w2, W2t, nullptr, 1024, 1024, 1048576L, 1048576L);

  // ---- out = hs, then sparse MoE adds (2 groups of 4 experts) ----
  hipMemcpyAsync(out, hs, 33554432, hipMemcpyDeviceToDevice, stream);
  for (int g = 0; g < 2; ++g) {
    // inter[e_local] = bf16(gelu(gather(n2) @ W1[e]) * wgt)
    sgemm_kernel<0, 2, 1><<<dim3(8, 64, 4), 256, 0, stream>>>(
        n1h, nullptr, W1t, nullptr, idxM, cntM, rwM, nullptr, interE,
        CD, CD, 1024, g * 4, 1048576L);
    // out[t] += inter[e_local] @ W2[e]
    sgemm_kernel<0, 3, 0><<<dim3(8, 64, 4), 256, 0, stream>>>(
        interE, nullptr, W2t, nullptr, idxM, cntM, rwM, out, nullptr,
        CD, CD, 1024, g * 4, 1048576L);
  }
}

// Round 8
// 752.949 us; speedup vs baseline: 2.1005x; 1.4605x over previous
//
#include <hip/hip_runtime.h>
#include <math.h>

typedef __bf16 bf16;
typedef __attribute__((ext_vector_type(8))) __bf16 bf16x8;
typedef __attribute__((ext_vector_type(4))) float f32x4;

#define LDSP(p) ((__attribute__((address_space(3))) void*)(p))
#define GLBP(p) ((const __attribute__((address_space(1))) void*)(p))

static constexpr int NTOK = 8192;   // B*T
static constexpr int CD   = 1024;   // C
static constexpr int HD   = 128;    // head dim
static constexpr int TS   = 2048;   // T
static constexpr int NB   = 4;      // B
static constexpr int CAP  = 8192;   // per-expert token capacity (hard bound)

__device__ __forceinline__ void split2(float x, bf16& h, bf16& l) {
  bf16 hh = (bf16)x;
  h = hh;
  l = (bf16)(x - (float)hh);
}

__device__ __forceinline__ float blk_sum(float v, float* sm) {
  #pragma unroll
  for (int o = 32; o > 0; o >>= 1) v += __shfl_down(v, o);
  if ((threadIdx.x & 63) == 0) sm[threadIdx.x >> 6] = v;
  __syncthreads();
  v = sm[0] + sm[1] + sm[2] + sm[3];
  __syncthreads();
  return v;
}

__device__ __forceinline__ float blk_max(float v, float* sm) {
  #pragma unroll
  for (int o = 32; o > 0; o >>= 1) v = fmaxf(v, __shfl_down(v, o));
  if ((threadIdx.x & 63) == 0) sm[threadIdx.x >> 6] = v;
  __syncthreads();
  v = fmaxf(fmaxf(sm[0], sm[1]), fmaxf(sm[2], sm[3]));
  __syncthreads();
  return v;
}

// ------- LayerNorm: fp32 out (for gating) + bf16 hi/lo split out ------------
__global__ __launch_bounds__(256) void ln_kernel(
    const float* __restrict__ x, const float* __restrict__ w, const float* __restrict__ b,
    float* __restrict__ outf, bf16* __restrict__ outh, bf16* __restrict__ outl)
{
  __shared__ float sm[4];
  size_t ro = (size_t)blockIdx.x * CD;
  float4 v = ((const float4*)(x + ro))[threadIdx.x];
  float s = v.x + v.y + v.z + v.w;
  s = blk_sum(s, sm);
  float mean = s * (1.f / CD);
  float dx = v.x - mean, dy = v.y - mean, dz = v.z - mean, dw = v.w - mean;
  float sq = dx*dx + dy*dy + dz*dz + dw*dw;
  sq = blk_sum(sq, sm);
  float rstd = rsqrtf(sq * (1.f / CD) + 1e-5f);
  float4 wv = ((const float4*)w)[threadIdx.x];
  float4 bv = ((const float4*)b)[threadIdx.x];
  float y0 = dx*rstd*wv.x + bv.x, y1 = dy*rstd*wv.y + bv.y;
  float y2 = dz*rstd*wv.z + bv.z, y3 = dw*rstd*wv.w + bv.w;
  ((float4*)(outf + ro))[threadIdx.x] = make_float4(y0, y1, y2, y3);
  size_t c0 = ro + (size_t)threadIdx.x * 4;
  split2(y0, outh[c0+0], outl[c0+0]);
  split2(y1, outh[c0+1], outl[c0+1]);
  split2(y2, outh[c0+2], outl[c0+2]);
  split2(y3, outh[c0+3], outl[c0+3]);
}

// ------- pre-normalize sim columns: simn[e][c] = sim[c][e]/max(||col||,eps) --
__global__ __launch_bounds__(256) void simn_prep(
    const float* __restrict__ sim, float* __restrict__ simn)
{
  __shared__ float sm[4];
  int e = blockIdx.x;
  float s = 0.f;
  for (int c = threadIdx.x; c < CD; c += 256) {
    float v = sim[(size_t)c * 8 + e];
    s += v * v;
  }
  s = blk_sum(s, sm);
  float inv = 1.f / fmaxf(sqrtf(s), 1e-12f);
  for (int c = threadIdx.x; c < CD; c += 256)
    simn[(size_t)e * CD + c] = sim[(size_t)c * 8 + e] * inv;
}

// ------- gate logits+softmax: 8 tokens/block, sim in LDS, no atomics --------
__global__ __launch_bounds__(256) void gate_logits(
    const float* __restrict__ nf, const float* __restrict__ simn,
    const float* __restrict__ gates, float* __restrict__ rw)
{
  __shared__ float simLds[8192];   // [e][c] : bank = c%32 -> 2-way (free)
  int tid = threadIdx.x;
  #pragma unroll
  for (int r = 0; r < 8; ++r)
    ((float4*)simLds)[tid + r * 256] = ((const float4*)simn)[tid + r * 256];
  __syncthreads();
  int w = tid >> 6, lane = tid & 63;
  #pragma unroll
  for (int it = 0; it < 2; ++it) {
    int t = blockIdx.x * 8 + w * 2 + it;
    const float* xr = nf + (size_t)t * CD;
    float acc[8] = {0,0,0,0,0,0,0,0};
    float nn = 0.f;
    #pragma unroll
    for (int cc = 0; cc < 16; ++cc) {
      int c = lane + cc * 64;
      float xv = xr[c];
      nn += xv * xv;
      #pragma unroll
      for (int e = 0; e < 8; ++e) acc[e] += xv * simLds[e * 1024 + c];
    }
    #pragma unroll
    for (int o = 1; o < 64; o <<= 1) {
      nn += __shfl_xor(nn, o);
      #pragma unroll
      for (int e = 0; e < 8; ++e) acc[e] += __shfl_xor(acc[e], o);
    }
    if (lane == 0) {
      float invn = 1.f / fmaxf(sqrtf(nn), 1e-12f);
      float logits[8], gated[8], mask[8];
      int act = 0;
      #pragma unroll
      for (int e = 0; e < 8; ++e) {
        float sg = 1.f / (1.f + expf(-gates[e]));
        float lg = acc[e] * invn - sg;
        logits[e] = lg;
        gated[e] = fmaxf(lg, 0.f);
        mask[e] = (gated[e] > 0.f) ? 1.f : 0.f;
        act += (gated[e] > 0.f) ? 1 : 0;
      }
      if (act == 0) {  // forced top-2, first-index tie semantics
        int i1 = 0;
        #pragma unroll
        for (int e = 1; e < 8; ++e) if (logits[e] > logits[i1]) i1 = e;
        int i2 = (i1 == 0) ? 1 : 0;
        #pragma unroll
        for (int e = 0; e < 8; ++e) if (e != i1 && e != i2 && logits[e] > logits[i2]) i2 = e;
        mask[i1] = 1.f; mask[i2] = 1.f;
      }
      float mx = -3.4e38f;
      #pragma unroll
      for (int e = 0; e < 8; ++e) if (mask[e] > 0.f) mx = fmaxf(mx, gated[e]);
      float ssum = 0.f, p[8];
      #pragma unroll
      for (int e = 0; e < 8; ++e) { p[e] = (mask[e] > 0.f) ? expf(gated[e] - mx) : 0.f; ssum += p[e]; }
      float inv = 1.f / ssum;
      #pragma unroll
      for (int e = 0; e < 8; ++e) rw[(size_t)t * 8 + e] = p[e] * inv;
    }
  }
}

// ------- build per-expert token lists: LDS-aggregated, 8 atomics/block ------
__global__ __launch_bounds__(256) void gate_lists(
    const float* __restrict__ rw, int* __restrict__ idxL, int* __restrict__ cnt)
{
  __shared__ int lcnt[8], base[8];
  int tid = threadIdx.x;
  if (tid < 8) lcnt[tid] = 0;
  __syncthreads();
  int t = blockIdx.x * 256 + tid;
  float4 r0 = ((const float4*)(rw + (size_t)t * 8))[0];
  float4 r1 = ((const float4*)(rw + (size_t)t * 8))[1];
  float pv[8] = {r0.x, r0.y, r0.z, r0.w, r1.x, r1.y, r1.z, r1.w};
  int pos0 = (pv[0] > 0.f) ? atomicAdd(&lcnt[0], 1) : -1;
  int pos1 = (pv[1] > 0.f) ? atomicAdd(&lcnt[1], 1) : -1;
  int pos2 = (pv[2] > 0.f) ? atomicAdd(&lcnt[2], 1) : -1;
  int pos3 = (pv[3] > 0.f) ? atomicAdd(&lcnt[3], 1) : -1;
  int pos4 = (pv[4] > 0.f) ? atomicAdd(&lcnt[4], 1) : -1;
  int pos5 = (pv[5] > 0.f) ? atomicAdd(&lcnt[5], 1) : -1;
  int pos6 = (pv[6] > 0.f) ? atomicAdd(&lcnt[6], 1) : -1;
  int pos7 = (pv[7] > 0.f) ? atomicAdd(&lcnt[7], 1) : -1;
  __syncthreads();
  if (tid < 8) base[tid] = atomicAdd(&cnt[tid], lcnt[tid]);
  __syncthreads();
  if (pos0 >= 0) idxL[(size_t)0 * CAP + base[0] + pos0] = t;
  if (pos1 >= 0) idxL[(size_t)1 * CAP + base[1] + pos1] = t;
  if (pos2 >= 0) idxL[(size_t)2 * CAP + base[2] + pos2] = t;
  if (pos3 >= 0) idxL[(size_t)3 * CAP + base[3] + pos3] = t;
  if (pos4 >= 0) idxL[(size_t)4 * CAP + base[4] + pos4] = t;
  if (pos5 >= 0) idxL[(size_t)5 * CAP + base[5] + pos5] = t;
  if (pos6 >= 0) idxL[(size_t)6 * CAP + base[6] + pos6] = t;
  if (pos7 >= 0) idxL[(size_t)7 * CAP + base[7] + pos7] = t;
}

// ------------- transpose + (optional) bf16 split: out[j][i] = src[i][j] -----
__global__ __launch_bounds__(256) void transpose_split(
    const float* __restrict__ src, bf16* __restrict__ dsth, bf16* __restrict__ dstl,
    int ldsrc, int lddst, long sBatch, long dBatch)
{
  __shared__ float tile[32][33];
  src  += (size_t)blockIdx.z * sBatch;
  dsth += (size_t)blockIdx.z * dBatch;
  if (dstl) dstl += (size_t)blockIdx.z * dBatch;
  int j0 = blockIdx.x * 32;   // src col
  int i0 = blockIdx.y * 32;   // src row
  int tx = threadIdx.x & 31, ty = threadIdx.x >> 5;
  #pragma unroll
  for (int r = 0; r < 32; r += 8)
    tile[ty + r][tx] = src[(size_t)(i0 + ty + r) * ldsrc + j0 + tx];
  __syncthreads();
  #pragma unroll
  for (int r = 0; r < 32; r += 8) {
    float v = tile[tx][ty + r];
    size_t o = (size_t)(j0 + ty + r) * lddst + i0 + tx;
    bf16 hh, ll; split2(v, hh, ll);
    dsth[o] = hh;
    if (dstl) dstl[o] = ll;
  }
}

// -------- dense GEMM (for attention scores / PV) ----------------------------
// EPI: 3 split-bf16 (v*scale) | 4 f32 atomicAdd. CAUSAL skip. KSPLIT chunks.
template<int SPLIT, int EPI, int CAUSAL, int KSPLIT>
__global__ __launch_bounds__(256) void gemm_kernel(
    const bf16* __restrict__ Ah, const bf16* __restrict__ Al,
    const bf16* __restrict__ Bh, const bf16* __restrict__ Bl,
    float* __restrict__ Co, bf16* __restrict__ outb,
    bf16* __restrict__ outb2, float scale,
    int M, int N, int K, long aB, long bB, long cB)
{
  int n0 = blockIdx.x * 128, m0 = blockIdx.y * 128;
  if (CAUSAL && n0 > m0) return;
  int bz = (KSPLIT > 1) ? (blockIdx.z / KSPLIT) : blockIdx.z;
  int kc0 = 0, kc1 = K;
  if constexpr (KSPLIT > 1) {
    int kch = blockIdx.z % KSPLIT;
    int Kc = K / KSPLIT;
    kc0 = kch * Kc; kc1 = kc0 + Kc;
  }
  const bf16* aH = Ah + (size_t)bz * aB + (size_t)m0 * K;
  const bf16* bH = Bh + (size_t)bz * bB + (size_t)n0 * K;
  const bf16* aL = nullptr; const bf16* bL = nullptr;
  if constexpr (SPLIT) {
    aL = Al + (size_t)bz * aB + (size_t)m0 * K;
    bL = Bl + (size_t)bz * bB + (size_t)n0 * K;
  }
  __shared__ bf16 As[SPLIT + 1][128 * 32];
  __shared__ bf16 Bs[SPLIT + 1][128 * 32];
  const f32x4 fz = {0.f, 0.f, 0.f, 0.f};
  f32x4 acc[4][4];
  #pragma unroll
  for (int i = 0; i < 4; ++i)
    #pragma unroll
    for (int j = 0; j < 4; ++j) acc[i][j] = fz;

  int lane = threadIdx.x & 63;
  int wv = threadIdx.x >> 6;
  int wr = wv >> 1, wc = wv & 1;
  int l15 = lane & 15;
  int kOff = (lane >> 4) * 8;
  int tt = threadIdx.x;

  for (int k0 = kc0; k0 < kc1; k0 += 32) {
    #pragma unroll
    for (int cch = 0; cch < 2; ++cch) {
      int ci = tt + cch * 256;
      int row = ci >> 2;
      int kc = (ci & 3) * 8;
      size_t go = (size_t)row * K + (size_t)(k0 + kc);
      __builtin_amdgcn_global_load_lds(GLBP(aH + go), LDSP(&As[0][ci * 8]), 16, 0, 0);
      __builtin_amdgcn_global_load_lds(GLBP(bH + go), LDSP(&Bs[0][ci * 8]), 16, 0, 0);
      if constexpr (SPLIT) {
        __builtin_amdgcn_global_load_lds(GLBP(aL + go), LDSP(&As[1][ci * 8]), 16, 0, 0);
        __builtin_amdgcn_global_load_lds(GLBP(bL + go), LDSP(&Bs[1][ci * 8]), 16, 0, 0);
      }
    }
    __syncthreads();
    bf16x8 aF[2][4], bF[2][4];
    #pragma unroll
    for (int i = 0; i < 4; ++i) {
      aF[0][i] = *(const bf16x8*)&As[0][(wr*64 + i*16 + l15) * 32 + kOff];
      bF[0][i] = *(const bf16x8*)&Bs[0][(wc*64 + i*16 + l15) * 32 + kOff];
      if constexpr (SPLIT) {
        aF[1][i] = *(const bf16x8*)&As[1][(wr*64 + i*16 + l15) * 32 + kOff];
        bF[1][i] = *(const bf16x8*)&Bs[1][(wc*64 + i*16 + l15) * 32 + kOff];
      }
    }
    #pragma unroll
    for (int i = 0; i < 4; ++i)
      #pragma unroll
      for (int j = 0; j < 4; ++j) {
        acc[i][j] = __builtin_amdgcn_mfma_f32_16x16x32_bf16(aF[0][i], bF[0][j], acc[i][j], 0, 0, 0);
        if constexpr (SPLIT) {
          acc[i][j] = __builtin_amdgcn_mfma_f32_16x16x32_bf16(aF[0][i], bF[1][j], acc[i][j], 0, 0, 0);
          acc[i][j] = __builtin_amdgcn_mfma_f32_16x16x32_bf16(aF[1][i], bF[0][j], acc[i][j], 0, 0, 0);
        }
      }
    __syncthreads();
  }

  size_t cz = (size_t)bz * cB;
  #pragma unroll
  for (int i = 0; i < 4; ++i) {
    #pragma unroll
    for (int j = 0; j < 4; ++j) {
      int r0 = m0 + wr*64 + i*16 + (lane >> 4) * 4;
      int ccol = n0 + wc*64 + j*16 + l15;
      #pragma unroll
      for (int jj = 0; jj < 4; ++jj) {
        float v = acc[i][j][jj];
        size_t idx = cz + (size_t)(r0 + jj) * N + ccol;
        if constexpr (EPI == 3) {
          split2(v * scale, outb[idx], outb2[idx]);
        } else {
          unsafeAtomicAdd(&Co[idx], v);
        }
      }
    }
  }
}

// ------ SPARSE expert GEMM: per-expert gathered rows, fixed grid ------------
template<int SPLIT, int EPI, int GATHER>
__global__ __launch_bounds__(256) void sgemm_kernel(
    const bf16* __restrict__ Ah, const bf16* __restrict__ Al,
    const bf16* __restrict__ Bh, const bf16* __restrict__ Bl,
    const int* __restrict__ idxL, const int* __restrict__ cnt,
    const float* __restrict__ rw, float* __restrict__ outF,
    bf16* __restrict__ outB,
    int lda, int K, int ldC, int eBase, long bB)
{
  int e = eBase + blockIdx.z;
  int count = cnt[e];
  int m0 = blockIdx.y * 128;
  if (m0 >= count) return;
  int n0 = blockIdx.x * 128;
  const int* myIdx = idxL + (size_t)e * CAP;
  const bf16* bH = Bh + (size_t)e * bB;
  const bf16* bL = nullptr;
  const bf16* aH = Ah;
  const bf16* aL = Al;
  if constexpr (SPLIT) bL = Bl + (size_t)e * bB;
  if constexpr (!GATHER) {
    aH += (size_t)blockIdx.z * CAP * lda;
    if constexpr (SPLIT) aL += (size_t)blockIdx.z * CAP * lda;
  }

  __shared__ bf16 As[SPLIT + 1][128 * 32];
  __shared__ bf16 Bs[SPLIT + 1][128 * 32];
  const f32x4 fz = {0.f, 0.f, 0.f, 0.f};
  f32x4 acc[4][4];
  #pragma unroll
  for (int i = 0; i < 4; ++i)
    #pragma unroll
    for (int j = 0; j < 4; ++j) acc[i][j] = fz;

  int lane = threadIdx.x & 63;
  int wv = threadIdx.x >> 6;
  int wr = wv >> 1, wc = wv & 1;
  int l15 = lane & 15;
  int kOff = (lane >> 4) * 8;
  int tt = threadIdx.x;

  int r1 = tt >> 2;
  int kcA = (tt & 3) * 8;
  int s1 = m0 + r1, s2 = s1 + 64;
  int ga1, ga2;
  if constexpr (GATHER) {
    ga1 = myIdx[s1 < count ? s1 : count - 1];
    ga2 = myIdx[s2 < count ? s2 : count - 1];
  } else { ga1 = s1; ga2 = s2; }
  size_t ao1 = (size_t)ga1 * lda, ao2 = (size_t)ga2 * lda;
  size_t bo1 = (size_t)(n0 + r1) * K, bo2 = (size_t)(n0 + r1 + 64) * K;

  for (int k0 = 0; k0 < K; k0 += 32) {
    size_t kk = (size_t)(k0 + kcA);
    __builtin_amdgcn_global_load_lds(GLBP(aH + ao1 + kk), LDSP(&As[0][tt * 8]), 16, 0, 0);
    __builtin_amdgcn_global_load_lds(GLBP(bH + bo1 + kk), LDSP(&Bs[0][tt * 8]), 16, 0, 0);
    __builtin_amdgcn_global_load_lds(GLBP(aH + ao2 + kk), LDSP(&As[0][(tt + 256) * 8]), 16, 0, 0);
    __builtin_amdgcn_global_load_lds(GLBP(bH + bo2 + kk), LDSP(&Bs[0][(tt + 256) * 8]), 16, 0, 0);
    if constexpr (SPLIT) {
      __builtin_amdgcn_global_load_lds(GLBP(aL + ao1 + kk), LDSP(&As[1][tt * 8]), 16, 0, 0);
      __builtin_amdgcn_global_load_lds(GLBP(bL + bo1 + kk), LDSP(&Bs[1][tt * 8]), 16, 0, 0);
      __builtin_amdgcn_global_load_lds(GLBP(aL + ao2 + kk), LDSP(&As[1][(tt + 256) * 8]), 16, 0, 0);
      __builtin_amdgcn_global_load_lds(GLBP(bL + bo2 + kk), LDSP(&Bs[1][(tt + 256) * 8]), 16, 0, 0);
    }
    __syncthreads();
    bf16x8 aF[2][4], bF[2][4];
    #pragma unroll
    for (int i = 0; i < 4; ++i) {
      aF[0][i] = *(const bf16x8*)&As[0][(wr*64 + i*16 + l15) * 32 + kOff];
      bF[0][i] = *(const bf16x8*)&Bs[0][(wc*64 + i*16 + l15) * 32 + kOff];
      if constexpr (SPLIT) {
        aF[1][i] = *(const bf16x8*)&As[1][(wr*64 + i*16 + l15) * 32 + kOff];
        bF[1][i] = *(const bf16x8*)&Bs[1][(wc*64 + i*16 + l15) * 32 + kOff];
      }
    }
    #pragma unroll
    for (int i = 0; i < 4; ++i)
      #pragma unroll
      for (int j = 0; j < 4; ++j) {
        acc[i][j] = __builtin_amdgcn_mfma_f32_16x16x32_bf16(aF[0][i], bF[0][j], acc[i][j], 0, 0, 0);
        if constexpr (SPLIT) {
          acc[i][j] = __builtin_amdgcn_mfma_f32_16x16x32_bf16(aF[0][i], bF[1][j], acc[i][j], 0, 0, 0);
          acc[i][j] = __builtin_amdgcn_mfma_f32_16x16x32_bf16(aF[1][i], bF[0][j], acc[i][j], 0, 0, 0);
        }
      }
    __syncthreads();
  }

  #pragma unroll
  for (int i = 0; i < 4; ++i) {
    #pragma unroll
    for (int jj = 0; jj < 4; ++jj) {
      int sl = m0 + wr*64 + i*16 + (lane >> 4) * 4 + jj;
      if (sl >= count) continue;
      int tok = myIdx[sl];
      float wgt = 0.f;
      if constexpr (EPI <= 2) wgt = rw[(size_t)tok * 8 + e];
      #pragma unroll
      for (int j = 0; j < 4; ++j) {
        int ccol = n0 + wc*64 + j*16 + l15;
        float v = acc[i][j][jj];
        if constexpr (EPI == 0) {
          unsafeAtomicAdd(&outF[(size_t)tok * ldC + ccol], wgt * v);
        } else if constexpr (EPI == 1) {
          unsafeAtomicAdd(&outF[(size_t)tok * 1024 + ccol], wgt * v);
        } else if constexpr (EPI == 2) {
          float gl = 0.5f * v * (1.f + erff(v * 0.70710678118654752f));
          outB[((size_t)blockIdx.z * CAP + sl) * 1024 + ccol] = (bf16)(gl * wgt);
        } else {
          unsafeAtomicAdd(&outF[(size_t)tok * 1024 + ccol], v);
        }
      }
    }
  }
}

// ------- causal softmax, IN-PLACE over split-bf16 scores -> split-bf16 P ----
__global__ __launch_bounds__(256) void softmax_kernel(
    bf16* __restrict__ ph, bf16* __restrict__ pl)
{
  __shared__ float sm[4];
  int t = blockIdx.x;
  size_t ro = ((size_t)blockIdx.y * TS + t) * TS;
  float vals[8];
  float mx = -3.4e38f;
  #pragma unroll
  for (int u = 0; u < 8; ++u) {
    int j = threadIdx.x + u * 256;
    float v = (j <= t) ? ((float)ph[ro + j] + (float)pl[ro + j]) : -3.4e38f;
    vals[u] = v;
    mx = fmaxf(mx, v);
  }
  mx = blk_max(mx, sm);
  float sum = 0.f;
  #pragma unroll
  for (int u = 0; u < 8; ++u) {
    int j = threadIdx.x + u * 256;
    float e = (j <= t) ? expf(vals[u] - mx) : 0.f;
    vals[u] = e;
    sum += e;
  }
  sum = blk_sum(sum, sm);
  float inv = 1.f / sum;
  #pragma unroll
  for (int u = 0; u < 8; ++u) {
    int j = threadIdx.x + u * 256;
    split2(vals[u] * inv, ph[ro + j], pl[ro + j]);
  }
}

// ------- qkv convert: fp32 accum (8192x384) -> split q,k + fp32 v -----------
__global__ __launch_bounds__(256) void qkv_cvt(
    const float* __restrict__ qkvF,
    bf16* __restrict__ qh, bf16* __restrict__ ql,
    bf16* __restrict__ kh, bf16* __restrict__ kl,
    float* __restrict__ vf)
{
  size_t i = (size_t)blockIdx.x * 256 + threadIdx.x;   // over 8192*128
  int t = (int)(i >> 7), h = (int)(i & 127);
  const float* row = qkvF + (size_t)t * 384;
  split2(row[h], qh[i], ql[i]);
  split2(row[128 + h], kh[i], kl[i]);
  vf[i] = row[256 + h];
}

// ------- attn split: fp32 attn (8192x128) -> split bf16 ---------------------
__global__ __launch_bounds__(256) void attn_split(
    const float* __restrict__ a, bf16* __restrict__ ah, bf16* __restrict__ al)
{
  size_t i = (size_t)blockIdx.x * 256 + threadIdx.x;
  split2(a[i], ah[i], al[i]);
}

// ============================================================================
extern "C" void kernel_launch(void* const* d_in, const int* in_sizes, int n_in,
                              void* d_out, int out_size, void* d_ws, size_t ws_size,
                              hipStream_t stream) {
  const float* x        = (const float*)d_in[0];
  const float* ln1w     = (const float*)d_in[1];
  const float* ln1b     = (const float*)d_in[2];
  const float* ln2w     = (const float*)d_in[3];
  const float* ln2b     = (const float*)d_in[4];
  const float* smha_sim = (const float*)d_in[5];
  const float* smha_g   = (const float*)d_in[6];
  const float* q_proj   = (const float*)d_in[7];
  const float* k_proj   = (const float*)d_in[8];
  const float* v_proj   = (const float*)d_in[9];
  const float* o_proj   = (const float*)d_in[10];
  const float* moe_sim  = (const float*)d_in[11];
  const float* moe_g    = (const float*)d_in[12];
  const float* w1       = (const float*)d_in[13];
  const float* w2       = (const float*)d_in[14];
  float* out = (float*)d_out;
  (void)in_sizes; (void)n_in; (void)out_size;

  // ---- workspace layout (~211 MB peak) ----
  char* ws = (char*)d_ws;
  size_t off = 0;
  auto alloc = [&](size_t bytes) -> char* {
    char* p = ws + off;
    off += (bytes + 255) & ~(size_t)255;
    return p;
  };
  float* hs    = (float*)alloc(33554432);   // x + attn_out (atomic target)
  bf16*  n1h   = (bf16*) alloc(16777216);   // LN split [LN1->QKV, LN2->MoE]
  bf16*  n1l   = (bf16*) alloc(16777216);
  float* rwA   = (float*)alloc(262144);
  float* rwM   = (float*)alloc(262144);
  int*   idxA  = (int*)  alloc(262144);     // 8 x 8192 token list
  int*   idxM  = (int*)  alloc(262144);
  int*   cnts  = (int*)  alloc(256);        // [0..7] attn, [8..15] moe
  float* simnA = (float*)alloc(32768);      // normalized sim^T [8][1024]
  float* simnM = (float*)alloc(32768);
  bf16*  OtH   = (bf16*) alloc(2097152);    // o_proj^T split (E,1024,128)
  bf16*  OtL   = (bf16*) alloc(2097152);
  bf16*  qh    = (bf16*) alloc(2097152);
  bf16*  ql    = (bf16*) alloc(2097152);
  bf16*  kh    = (bf16*) alloc(2097152);
  bf16*  kl    = (bf16*) alloc(2097152);
  float* vf    = (float*)alloc(4194304);
  bf16*  vth   = (bf16*) alloc(2097152);
  bf16*  vtl   = (bf16*) alloc(2097152);
  float* attnF = (float*)alloc(4194304);    // PV atomic target (8192x128 f32)
  bf16*  atth  = (bf16*) alloc(2097152);
  bf16*  attl  = (bf16*) alloc(2097152);
  float* qkvF  = (float*)alloc(12582912);   // QKV atomic accum (8192x384 f32)
  char*  segW  = alloc(33554432);           // Wqkv split (25.2MB) | W1t+W2t (33.5MB)
  char*  segB  = alloc(67108864);           // n1f | Ph+Pl | n2f | interE (aliased)
  size_t NEED = off;
  if (ws_size < NEED) return;

  bf16* WqkvH = (bf16*)segW;                      // (E, 384, 1024) rows q|k|v
  bf16* WqkvL = (bf16*)(segW + 12582912);
  bf16* W1t   = (bf16*)segW;                      // (E, 1024, 1024) B^T
  bf16* W2t   = (bf16*)(segW + 16777216);
  float* n1f  = (float*)segB;                     // fp32 LN out (gating input)
  bf16* Ph    = (bf16*)segB;                      // scores then P, in-place
  bf16* Pl    = (bf16*)(segB + 33554432);
  bf16* interE= (bf16*)segB;                      // 4 experts x 8192 x 1024

  int* cntA = cnts;
  int* cntM = cnts + 8;

  // ---- zero dynamic accumulators / counters (graph-safe) ----
  hipMemsetAsync(cnts, 0, 256, stream);
  hipMemsetAsync(qkvF, 0, 12582912, stream);
  hipMemsetAsync(attnF, 0, 4194304, stream);

  // ---- attention weights: transpose + split (per-expert B^T layouts) ----
  transpose_split<<<dim3(4, 32, 8), 256, 0, stream>>>(q_proj, WqkvH,          WqkvL,          128, 1024, 131072L, 393216L);
  transpose_split<<<dim3(4, 32, 8), 256, 0, stream>>>(k_proj, WqkvH + 131072, WqkvL + 131072, 128, 1024, 131072L, 393216L);
  transpose_split<<<dim3(4, 32, 8), 256, 0, stream>>>(v_proj, WqkvH + 262144, WqkvL + 262144, 128, 1024, 131072L, 393216L);
  transpose_split<<<dim3(32, 4, 8), 256, 0, stream>>>(o_proj, OtH, OtL, 1024, 128, 131072L, 131072L);
  simn_prep<<<8, 256, 0, stream>>>(smha_sim, simnA);
  simn_prep<<<8, 256, 0, stream>>>(moe_sim, simnM);

  // ---- LN1 + attention gating (logits, then lists) ----
  ln_kernel<<<NTOK, 256, 0, stream>>>(x, ln1w, ln1b, n1f, n1h, n1l);
  gate_logits<<<NTOK / 8, 256, 0, stream>>>(n1f, simnA, smha_g, rwA);
  gate_lists<<<NTOK / 256, 256, 0, stream>>>(rwA, idxA, cntA);

  // ---- sparse QKV: per-expert gathered GEMM, atomic wgt*v into qkvF ----
  sgemm_kernel<1, 0, 1><<<dim3(3, 64, 8), 256, 0, stream>>>(
      n1h, n1l, WqkvH, WqkvL, idxA, cntA, rwA, qkvF, nullptr,
      CD, CD, 384, 0, 393216L);
  qkv_cvt<<<4096, 256, 0, stream>>>(qkvF, qh, ql, kh, kl, vf);
  transpose_split<<<dim3(4, 64, 4), 256, 0, stream>>>(vf, vth, vtl, 128, 2048, 262144L, 262144L);

  // ---- attention: scores (split, scale folded) -> softmax -> PV(split-K) ----
  gemm_kernel<1, 3, 1, 1><<<dim3(16, 16, 4), 256, 0, stream>>>(
      qh, ql, kh, kl, nullptr, Ph, Pl, 0.08838834764831845f,
      TS, TS, HD, (long)TS * HD, (long)TS * HD, (long)TS * TS);
  softmax_kernel<<<dim3(TS, NB), 256, 0, stream>>>(Ph, Pl);
  gemm_kernel<1, 4, 0, 4><<<dim3(1, 16, 16), 256, 0, stream>>>(
      Ph, Pl, vth, vtl, attnF, nullptr, nullptr, 1.f,
      TS, HD, TS, (long)TS * TS, (long)HD * TS, (long)TS * HD);

  // ---- sparse O-proj: hs = x + sum_e wgt*(attn @ Wo[e]) ----
  attn_split<<<4096, 256, 0, stream>>>(attnF, atth, attl);
  hipMemcpyAsync(hs, x, 33554432, hipMemcpyDeviceToDevice, stream);
  sgemm_kernel<1, 1, 1><<<dim3(8, 64, 8), 256, 0, stream>>>(
      atth, attl, OtH, OtL, idxA, cntA, rwA, hs, nullptr,
      HD, HD, CD, 0, 131072L);

  // ---- LN2 + MoE gating ----
  ln_kernel<<<NTOK, 256, 0, stream>>>(hs, ln2w, ln2b, n1f, n1h, n1l);  // n2
  gate_logits<<<NTOK / 8, 256, 0, stream>>>(n1f, simnM, moe_g, rwM);
  gate_lists<<<NTOK / 256, 256, 0, stream>>>(rwM, idxM, cntM);

  // ---- MoE weights (plain bf16, overwrite Wqkv region) ----
  transpose_split<<<dim3(32, 32, 8), 256, 0, stream>>>(w1, W1t, nullptr, 1024, 1024, 1048576L, 1048576L);
  transpose_split<<<dim3(32, 32, 8), 256, 0, stream>>>(w2, W2t, nullptr, 1024, 1024, 1048576L, 1048576L);

  // ---- out = hs, then sparse MoE adds (2 groups of 4 experts) ----
  hipMemcpyAsync(out, hs, 33554432, hipMemcpyDeviceToDevice, stream);
  for (int g = 0; g < 2; ++g) {
    sgemm_kernel<0, 2, 1><<<dim3(8, 64, 4), 256, 0, stream>>>(
        n1h, nullptr, W1t, nullptr, idxM, cntM, rwM, nullptr, interE,
        CD, CD, 1024, g * 4, 1048576L);
    sgemm_kernel<0, 3, 0><<<dim3(8, 64, 4), 256, 0, stream>>>(
        interE, nullptr, W2t, nullptr, idxM, cntM, rwM, out, nullptr,
        CD, CD, 1024, g * 4, 1048576L);
  }
}